// Round 6
// baseline (3213.875 us; speedup 1.0000x reference)
//
#include <hip/hip_runtime.h>

// Problem constants (B=8, T=1, H=56, C=512, nh=8, d=64)
// Inputs: float32. Output: FLOAT32 (npz-size evidence, round 5). ws: bf16.
#define NH    8
#define DH    64
#define NTOK  3137      // 56*56+1
#define NOUT  785       // 28*28+1
#define CDIM  512
#define ROWS  6280      // 8*785
#define HO    28
#define HIN   56

typedef unsigned short u16;

__device__ __forceinline__ float b2f(u16 u) { return __uint_as_float(((unsigned)u) << 16); }
__device__ __forceinline__ u16 f2b(float f) {
  unsigned u = __float_as_uint(f);
  return (u16)((u + 0x7FFFu + ((u >> 16) & 1u)) >> 16);
}

// ---------------------------------------------------------------------------
// Kernel 1: depthwise 3x3 stride-2 pool + LayerNorm(64), for q/k/v.
// One 64-lane wave per (pooled token, b*h). Output bf16:
// P[(b*785+n)*512 + h*64+d]  (the _lin GEMM input layout).
// ---------------------------------------------------------------------------
__global__ __launch_bounds__(64) void pool_ln_kernel(
    const float* __restrict__ x, const float* __restrict__ xr,
    const float* __restrict__ cwq, const float* __restrict__ cwk, const float* __restrict__ cwv,
    const float* __restrict__ gq, const float* __restrict__ bq,
    const float* __restrict__ gk, const float* __restrict__ bk,
    const float* __restrict__ gv, const float* __restrict__ bv,
    u16* __restrict__ Pq, u16* __restrict__ Pk, u16* __restrict__ Pv)
{
  int n     = blockIdx.x;       // 0..784
  int bh    = blockIdx.y;       // b*8 + h
  int which = blockIdx.z;       // 0=q(x), 1=k(x_ref), 2=v(x_ref)
  int b = bh >> 3, h = bh & 7;
  int di = threadIdx.x;

  const float* src = (which == 0) ? x : xr;
  const float* cw  = (which == 0) ? cwq : (which == 1 ? cwk : cwv);
  const float* g   = (which == 0) ? gq  : (which == 1 ? gk  : gv);
  const float* be  = (which == 0) ? bq  : (which == 1 ? bk  : bv);
  u16* P           = (which == 0) ? Pq  : (which == 1 ? Pk  : Pv);

  size_t srcbase = (size_t)b * NTOK * CDIM + (size_t)h * DH + di;

  float val;
  if (n == 0) {
    val = src[srcbase];                       // cls token (token 0)
  } else {
    int oy = (n - 1) / HO, ox = (n - 1) % HO;
    float acc = 0.f;
#pragma unroll
    for (int ky = 0; ky < 3; ++ky) {
      int iy = oy * 2 - 1 + ky;
      if (iy < 0 || iy >= HIN) continue;
#pragma unroll
      for (int kx = 0; kx < 3; ++kx) {
        int ix = ox * 2 - 1 + kx;
        if (ix < 0 || ix >= HIN) continue;
        int tok = 1 + iy * HIN + ix;
        acc += src[srcbase + (size_t)tok * CDIM] * cw[(ky * 3 + kx) * DH + di];
      }
    }
    val = acc;
  }

  // wave-64 LayerNorm over d
  float s = val, sq = val * val;
#pragma unroll
  for (int off = 32; off > 0; off >>= 1) {
    s  += __shfl_xor(s, off, 64);
    sq += __shfl_xor(sq, off, 64);
  }
  float mu  = s * (1.f / 64.f);
  float var = sq * (1.f / 64.f) - mu * mu;
  float o = (val - mu) * rsqrtf(var + 1e-5f) * g[di] + be[di];

  P[(size_t)(b * NOUT + n) * CDIM + h * DH + di] = f2b(o);
}

// ---------------------------------------------------------------------------
// Kernel 2: GEMM  Y[r,co] = sum_ci X[r,ci] * W[co,ci] + bias[co]
// X bf16 (ROWS x 512), W/bias float32 inputs.  fp32 accumulation.
// mode 1: write bf16 into (b,h,n,d) layout for attention (Yb16).
// mode 2: write FLOAT row-major (Yf32) -> d_out.
// 64x64 tile, BK=16, 256 threads, 4x4 per thread.
// ---------------------------------------------------------------------------
__global__ __launch_bounds__(256) void gemm_kernel(
    const u16* __restrict__ X, const float* __restrict__ W, const float* __restrict__ bias,
    u16* __restrict__ Yb16, float* __restrict__ Yf32, int R, int mode)
{
  __shared__ float Xs[16][65];
  __shared__ float Ws[16][65];

  int tid = threadIdx.x;
  int tx = tid & 15, ty = tid >> 4;
  int r0 = blockIdx.x * 64;
  int n0 = blockIdx.y * 64;

  float acc[4][4] = {};

  for (int k0 = 0; k0 < CDIM; k0 += 16) {
    int row = tid >> 2, kc = (tid & 3) * 4;
    {
      int r = r0 + row;
      float fx0 = 0.f, fx1 = 0.f, fx2 = 0.f, fx3 = 0.f;
      if (r < R) {
        ushort4 xv = *(const ushort4*)(X + (size_t)r * CDIM + k0 + kc);
        fx0 = b2f(xv.x); fx1 = b2f(xv.y); fx2 = b2f(xv.z); fx3 = b2f(xv.w);
      }
      Xs[kc + 0][row] = fx0; Xs[kc + 1][row] = fx1;
      Xs[kc + 2][row] = fx2; Xs[kc + 3][row] = fx3;

      int co = n0 + row;
      float4 wv = *(const float4*)(W + (size_t)co * CDIM + k0 + kc);
      Ws[kc + 0][row] = wv.x; Ws[kc + 1][row] = wv.y;
      Ws[kc + 2][row] = wv.z; Ws[kc + 3][row] = wv.w;
    }
    __syncthreads();
#pragma unroll
    for (int kk = 0; kk < 16; ++kk) {
      float a0 = Xs[kk][ty * 4 + 0], a1 = Xs[kk][ty * 4 + 1];
      float a2 = Xs[kk][ty * 4 + 2], a3 = Xs[kk][ty * 4 + 3];
      float w0 = Ws[kk][tx * 4 + 0], w1 = Ws[kk][tx * 4 + 1];
      float w2 = Ws[kk][tx * 4 + 2], w3 = Ws[kk][tx * 4 + 3];
      acc[0][0] += a0 * w0; acc[0][1] += a0 * w1; acc[0][2] += a0 * w2; acc[0][3] += a0 * w3;
      acc[1][0] += a1 * w0; acc[1][1] += a1 * w1; acc[1][2] += a1 * w2; acc[1][3] += a1 * w3;
      acc[2][0] += a2 * w0; acc[2][1] += a2 * w1; acc[2][2] += a2 * w2; acc[2][3] += a2 * w3;
      acc[3][0] += a3 * w0; acc[3][1] += a3 * w1; acc[3][2] += a3 * w2; acc[3][3] += a3 * w3;
    }
    __syncthreads();
  }

#pragma unroll
  for (int i = 0; i < 4; ++i) {
    int r = r0 + ty * 4 + i;
    if (r >= R) continue;
#pragma unroll
    for (int j = 0; j < 4; ++j) {
      int co = n0 + tx * 4 + j;
      float v = acc[i][j] + bias[co];
      if (mode == 1) {
        int b = r / NOUT, n = r % NOUT;
        Yb16[(((size_t)b * NH + (co >> 6)) * NOUT + n) * DH + (co & 63)] = f2b(v);
      } else {
        Yf32[(size_t)r * CDIM + co] = v;
      }
    }
  }
}

// ---------------------------------------------------------------------------
// Kernel 3: attention for one (b,h,query) per block.
// scores = SCALE*q.K^T + relpos bias; softmax; out = P.V / sum + residual q.
// Q/K/V bf16 in (b,h,n,d); rel_pos f32; writes O bf16 [(b*785+qi)*512+h*64+d].
// ---------------------------------------------------------------------------
__global__ __launch_bounds__(256) void attn_kernel(
    const u16* __restrict__ Q, const u16* __restrict__ K, const u16* __restrict__ V,
    const float* __restrict__ rph, const float* __restrict__ rpw,
    u16* __restrict__ O)
{
  __shared__ float qrow[64];
  __shared__ float relh[28];
  __shared__ float relw[28];
  __shared__ float sc[NOUT];
  __shared__ float red[256];
  __shared__ float Ks[128][65];
  __shared__ float pv[4][64];

  int tid = threadIdx.x;
  int qi  = blockIdx.x;
  int bh  = blockIdx.y;
  size_t base = (size_t)bh * NOUT * DH;

  if (tid < 64) qrow[tid] = b2f(Q[base + (size_t)qi * DH + tid]);
  __syncthreads();

  // relative-position bias rows (only for non-cls queries); uses UNSCALED q
  if (qi > 0 && tid < 56) {
    int qy = (qi - 1) / HO, qx = (qi - 1) % HO;
    float s = 0.f;
    if (tid < 28) {
      const float* rp = rph + (size_t)(qy - tid + 27) * DH;
#pragma unroll
      for (int d2 = 0; d2 < 64; ++d2) s += qrow[d2] * rp[d2];
      relh[tid] = s;
    } else {
      int kx = tid - 28;
      const float* rp = rpw + (size_t)(qx - kx + 27) * DH;
#pragma unroll
      for (int d2 = 0; d2 < 64; ++d2) s += qrow[d2] * rp[d2];
      relw[kx] = s;
    }
  }

  // QK^T in chunks of 128 keys staged in LDS (padded stride 65: conflict-free)
  for (int c0 = 0; c0 < NOUT; c0 += 128) {
    int cnt = min(128, NOUT - c0);
    __syncthreads();  // Ks reuse; also orders relh/relw/qrow writes before reads
    for (int idx = tid; idx < cnt * 64; idx += 256) {
      Ks[idx >> 6][idx & 63] = b2f(K[base + (size_t)(c0 + (idx >> 6)) * DH + (idx & 63)]);
    }
    __syncthreads();
    if (tid < cnt) {
      int ki = c0 + tid;
      float s = 0.f;
#pragma unroll
      for (int d2 = 0; d2 < 64; ++d2) s += qrow[d2] * Ks[tid][d2];
      s *= 0.125f;  // 64^-0.5
      if (qi > 0 && ki > 0) s += relh[(ki - 1) / HO] + relw[(ki - 1) % HO];
      sc[ki] = s;
    }
  }
  __syncthreads();

  // softmax (two-pass, block reduce)
  float m = -1e30f;
  for (int ki = tid; ki < NOUT; ki += 256) m = fmaxf(m, sc[ki]);
  red[tid] = m;
  __syncthreads();
  for (int sft = 128; sft > 0; sft >>= 1) {
    if (tid < sft) red[tid] = fmaxf(red[tid], red[tid + sft]);
    __syncthreads();
  }
  float M = red[0];
  __syncthreads();
  float ls = 0.f;
  for (int ki = tid; ki < NOUT; ki += 256) {
    float p = __expf(sc[ki] - M);
    sc[ki] = p;
    ls += p;
  }
  red[tid] = ls;
  __syncthreads();
  for (int sft = 128; sft > 0; sft >>= 1) {
    if (tid < sft) red[tid] += red[tid + sft];
    __syncthreads();
  }
  float S = red[0];
  __syncthreads();

  // P*V (4-way split over keys) + residual
  {
    int di = tid & 63, part = tid >> 6;
    float acc = 0.f;
    for (int ki = part; ki < NOUT; ki += 4)
      acc += sc[ki] * b2f(V[base + (size_t)ki * DH + di]);
    pv[part][di] = acc;
  }
  __syncthreads();
  if (tid < 64) {
    float o = (pv[0][tid] + pv[1][tid] + pv[2][tid] + pv[3][tid]) / S;
    if (qi > 0) o += qrow[tid];
    int b = bh >> 3, h = bh & 7;
    O[((size_t)b * NOUT + qi) * CDIM + h * DH + tid] = f2b(o);
  }
}

// ---------------------------------------------------------------------------
// Workspace schedule (bf16, PSZ = ROWS*CDIM = 3,215,360 elems = 6.43 MB each):
//   pool:   ws0=Pq, ws1=Pk, ws2=Pv
//   gemm q: Pq(ws0)  -> Qp(d_out scratch; d_out is PSZ f32 = 2*PSZ u16 capacity)
//   gemm k: Pk(ws1)  -> Kp(ws0)
//   gemm v: Pv(ws2)  -> Vp(ws1)
//   attn:   Qp,Kp,Vp -> O(ws2)
//   proj:   O(ws2)   -> d_out (FLOAT, overwrites Q scratch; Q dead by then)
// Peak d_ws usage: 3 buffers = 19.3 MB.
// ---------------------------------------------------------------------------
extern "C" void kernel_launch(void* const* d_in, const int* in_sizes, int n_in,
                              void* d_out, int out_size, void* d_ws, size_t ws_size,
                              hipStream_t stream) {
  const float* x     = (const float*)d_in[0];
  const float* xr    = (const float*)d_in[1];
  const float* wq    = (const float*)d_in[2];
  const float* bq    = (const float*)d_in[3];
  const float* wk    = (const float*)d_in[4];
  const float* bk    = (const float*)d_in[5];
  const float* wv    = (const float*)d_in[6];
  const float* bv    = (const float*)d_in[7];
  const float* wpj   = (const float*)d_in[8];
  const float* bpj   = (const float*)d_in[9];
  const float* cwq   = (const float*)d_in[10];
  const float* cwk   = (const float*)d_in[11];
  const float* cwv   = (const float*)d_in[12];
  const float* gq    = (const float*)d_in[13];
  const float* lbq   = (const float*)d_in[14];
  const float* gk    = (const float*)d_in[15];
  const float* lbk   = (const float*)d_in[16];
  const float* gv    = (const float*)d_in[17];
  const float* lbv   = (const float*)d_in[18];
  const float* rph   = (const float*)d_in[19];
  const float* rpw   = (const float*)d_in[20];
  (void)in_sizes; (void)n_in; (void)out_size; (void)ws_size;

  u16* ws = (u16*)d_ws;
  const size_t PSZ = (size_t)ROWS * CDIM;
  u16* ws0 = ws + 0 * PSZ;
  u16* ws1 = ws + 1 * PSZ;
  u16* ws2 = ws + 2 * PSZ;
  u16* qbuf = (u16*)d_out;   // bf16 scratch inside the f32 output buffer

  // 1) pool + layernorm for q/k/v
  pool_ln_kernel<<<dim3(NOUT, 64, 3), 64, 0, stream>>>(
      x, xr, cwq, cwk, cwv, gq, lbq, gk, lbk, gv, lbv, ws0, ws1, ws2);

  // 2) q/k/v linear projections -> (b,h,n,d) bf16
  dim3 ggrid((ROWS + 63) / 64, CDIM / 64);
  gemm_kernel<<<ggrid, 256, 0, stream>>>(ws0, wq, bq, qbuf, nullptr, ROWS, 1);
  gemm_kernel<<<ggrid, 256, 0, stream>>>(ws1, wk, bk, ws0,  nullptr, ROWS, 1);
  gemm_kernel<<<ggrid, 256, 0, stream>>>(ws2, wv, bv, ws1,  nullptr, ROWS, 1);

  // 3) attention with rel-pos bias + residual -> O in ws2
  attn_kernel<<<dim3(NOUT, 64), 256, 0, stream>>>(qbuf, ws0, ws1, rph, rpw, ws2);

  // 4) output projection -> FLOAT d_out
  gemm_kernel<<<ggrid, 256, 0, stream>>>(ws2, wpj, bpj, nullptr, (float*)d_out, ROWS, 2);
}

// Round 7
// 635.024 us; speedup vs baseline: 5.0610x; 5.0610x over previous
//
#include <hip/hip_runtime.h>

// Problem constants (B=8, T=1, H=56, C=512, nh=8, d=64)
// Inputs: float32. Output: float32. ws intermediates: bf16.
#define NH    8
#define DH    64
#define NTOK  3137      // 56*56+1
#define NOUT  785       // 28*28+1
#define CDIM  512
#define ROWS  6280      // 8*785
#define HO    28
#define HIN   56
#define NKT   13        // ceil(785/64) key tiles

typedef unsigned short u16;
typedef __attribute__((ext_vector_type(8))) short bf16x8;   // 8 bf16 = 4 VGPRs
typedef __attribute__((ext_vector_type(4))) float f32x4;    // MFMA C/D

__device__ __forceinline__ float b2f(u16 u) { return __uint_as_float(((unsigned)u) << 16); }
__device__ __forceinline__ u16 f2b(float f) {
  unsigned u = __float_as_uint(f);
  return (u16)((u + 0x7FFFu + ((u >> 16) & 1u)) >> 16);
}

// ---------------------------------------------------------------------------
// Kernel 1: depthwise 3x3 stride-2 pool + LayerNorm(64) (unchanged, verified)
// ---------------------------------------------------------------------------
__global__ __launch_bounds__(64) void pool_ln_kernel(
    const float* __restrict__ x, const float* __restrict__ xr,
    const float* __restrict__ cwq, const float* __restrict__ cwk, const float* __restrict__ cwv,
    const float* __restrict__ gq, const float* __restrict__ bq,
    const float* __restrict__ gk, const float* __restrict__ bk,
    const float* __restrict__ gv, const float* __restrict__ bv,
    u16* __restrict__ Pq, u16* __restrict__ Pk, u16* __restrict__ Pv)
{
  int n     = blockIdx.x;
  int bh    = blockIdx.y;
  int which = blockIdx.z;
  int b = bh >> 3, h = bh & 7;
  int di = threadIdx.x;

  const float* src = (which == 0) ? x : xr;
  const float* cw  = (which == 0) ? cwq : (which == 1 ? cwk : cwv);
  const float* g   = (which == 0) ? gq  : (which == 1 ? gk  : gv);
  const float* be  = (which == 0) ? bq  : (which == 1 ? bk  : bv);
  u16* P           = (which == 0) ? Pq  : (which == 1 ? Pk  : Pv);

  size_t srcbase = (size_t)b * NTOK * CDIM + (size_t)h * DH + di;

  float val;
  if (n == 0) {
    val = src[srcbase];
  } else {
    int oy = (n - 1) / HO, ox = (n - 1) % HO;
    float acc = 0.f;
#pragma unroll
    for (int ky = 0; ky < 3; ++ky) {
      int iy = oy * 2 - 1 + ky;
      if (iy < 0 || iy >= HIN) continue;
#pragma unroll
      for (int kx = 0; kx < 3; ++kx) {
        int ix = ox * 2 - 1 + kx;
        if (ix < 0 || ix >= HIN) continue;
        int tok = 1 + iy * HIN + ix;
        acc += src[srcbase + (size_t)tok * CDIM] * cw[(ky * 3 + kx) * DH + di];
      }
    }
    val = acc;
  }

  float s = val, sq = val * val;
#pragma unroll
  for (int off = 32; off > 0; off >>= 1) {
    s  += __shfl_xor(s, off, 64);
    sq += __shfl_xor(sq, off, 64);
  }
  float mu  = s * (1.f / 64.f);
  float var = sq * (1.f / 64.f) - mu * mu;
  float o = (val - mu) * rsqrtf(var + 1e-5f) * g[di] + be[di];

  P[(size_t)(b * NOUT + n) * CDIM + h * DH + di] = f2b(o);
}

// ---------------------------------------------------------------------------
// Kernel 2: GEMM (unchanged, verified)
// ---------------------------------------------------------------------------
__global__ __launch_bounds__(256) void gemm_kernel(
    const u16* __restrict__ X, const float* __restrict__ W, const float* __restrict__ bias,
    u16* __restrict__ Yb16, float* __restrict__ Yf32, int R, int mode)
{
  __shared__ float Xs[16][65];
  __shared__ float Ws[16][65];

  int tid = threadIdx.x;
  int tx = tid & 15, ty = tid >> 4;
  int r0 = blockIdx.x * 64;
  int n0 = blockIdx.y * 64;

  float acc[4][4] = {};

  for (int k0 = 0; k0 < CDIM; k0 += 16) {
    int row = tid >> 2, kc = (tid & 3) * 4;
    {
      int r = r0 + row;
      float fx0 = 0.f, fx1 = 0.f, fx2 = 0.f, fx3 = 0.f;
      if (r < R) {
        ushort4 xv = *(const ushort4*)(X + (size_t)r * CDIM + k0 + kc);
        fx0 = b2f(xv.x); fx1 = b2f(xv.y); fx2 = b2f(xv.z); fx3 = b2f(xv.w);
      }
      Xs[kc + 0][row] = fx0; Xs[kc + 1][row] = fx1;
      Xs[kc + 2][row] = fx2; Xs[kc + 3][row] = fx3;

      int co = n0 + row;
      float4 wv = *(const float4*)(W + (size_t)co * CDIM + k0 + kc);
      Ws[kc + 0][row] = wv.x; Ws[kc + 1][row] = wv.y;
      Ws[kc + 2][row] = wv.z; Ws[kc + 3][row] = wv.w;
    }
    __syncthreads();
#pragma unroll
    for (int kk = 0; kk < 16; ++kk) {
      float a0 = Xs[kk][ty * 4 + 0], a1 = Xs[kk][ty * 4 + 1];
      float a2 = Xs[kk][ty * 4 + 2], a3 = Xs[kk][ty * 4 + 3];
      float w0 = Ws[kk][tx * 4 + 0], w1 = Ws[kk][tx * 4 + 1];
      float w2 = Ws[kk][tx * 4 + 2], w3 = Ws[kk][tx * 4 + 3];
      acc[0][0] += a0 * w0; acc[0][1] += a0 * w1; acc[0][2] += a0 * w2; acc[0][3] += a0 * w3;
      acc[1][0] += a1 * w0; acc[1][1] += a1 * w1; acc[1][2] += a1 * w2; acc[1][3] += a1 * w3;
      acc[2][0] += a2 * w0; acc[2][1] += a2 * w1; acc[2][2] += a2 * w2; acc[2][3] += a2 * w3;
      acc[3][0] += a3 * w0; acc[3][1] += a3 * w1; acc[3][2] += a3 * w2; acc[3][3] += a3 * w3;
    }
    __syncthreads();
  }

#pragma unroll
  for (int i = 0; i < 4; ++i) {
    int r = r0 + ty * 4 + i;
    if (r >= R) continue;
#pragma unroll
    for (int j = 0; j < 4; ++j) {
      int co = n0 + tx * 4 + j;
      float v = acc[i][j] + bias[co];
      if (mode == 1) {
        int b = r / NOUT, n = r % NOUT;
        Yb16[(((size_t)b * NH + (co >> 6)) * NOUT + n) * DH + (co & 63)] = f2b(v);
      } else {
        Yf32[(size_t)r * CDIM + co] = v;
      }
    }
  }
}

// ---------------------------------------------------------------------------
// Kernel 3: flash-style MFMA attention.
// Block = 256 threads = 4 waves; one block per (bh, 64-query tile).
// Wave w owns queries [qt*64 + w*16, +16). Keys streamed in tiles of 64.
// MFMA 16x16x32 bf16. Layouts (per guide §3, m89-verified C/D):
//   A: row = lane&15, k = (lane>>4)*8 + i   (8 contiguous bf16 -> b128 load)
//   B: col = lane&15, k = (lane>>4)*8 + i
//   D: col = lane&15, row = (lane>>4)*4 + j
// ---------------------------------------------------------------------------
__global__ __launch_bounds__(256) void fattn_kernel(
    const u16* __restrict__ Q, const u16* __restrict__ K, const u16* __restrict__ V,
    const float* __restrict__ rph, const float* __restrict__ rpw,
    u16* __restrict__ O)
{
  __shared__ u16 Qs[64][72];       // [q][d], pad to 72 (144B rows)
  __shared__ u16 Vs[64][72];       // [d][k] transposed V tile
  __shared__ u16 Ps[4][16][72];    // per-wave P bounce [q16][k64]
  __shared__ float relh[64][28];   // q . Rh[qy-ky+27]
  __shared__ float relw[64][28];   // q . Rw[qx-kx+27]

  int tid = threadIdx.x;
  int qt = blockIdx.x, bh = blockIdx.y;
  int w = tid >> 6, lane = tid & 63, l15 = lane & 15, lg = lane >> 4;
  size_t base = (size_t)bh * NOUT * DH;
  int q0 = qt * 64;

  // ---- stage Q tile (rows clamped; invalid rows masked at write) ----
  {
    int q = tid >> 2, d0 = (tid & 3) * 16;
    int qi = min(q0 + q, NOUT - 1);
    const u16* src = Q + base + (size_t)qi * DH + d0;
    bf16x8 a = *(const bf16x8*)(src);
    bf16x8 b = *(const bf16x8*)(src + 8);
    *(bf16x8*)&Qs[q][d0]     = a;
    *(bf16x8*)&Qs[q][d0 + 8] = b;
  }
  __syncthreads();

  // ---- per-block rel-pos bias tables ----
  for (int idx = tid; idx < 64 * 28; idx += 256) {
    int q = idx / 28, kc = idx % 28;
    int qi = q0 + q;
    float vh = 0.f, vw = 0.f;
    if (qi >= 1 && qi < NOUT) {
      int qy = (qi - 1) / HO, qx = (qi - 1) % HO;
      const float* rh = rph + (size_t)(qy - kc + 27) * DH;
      const float* rw = rpw + (size_t)(qx - kc + 27) * DH;
      for (int d = 0; d < DH; ++d) {
        float qv = b2f(Qs[q][d]);
        vh += qv * rh[d];
        vw += qv * rw[d];
      }
    }
    relh[q][kc] = vh;
    relw[q][kc] = vw;
  }

  // ---- Q A-fragments (constant across key tiles) ----
  int qrow = w * 16 + l15;
  bf16x8 qa0 = *(const bf16x8*)&Qs[qrow][lg * 8];
  bf16x8 qa1 = *(const bf16x8*)&Qs[qrow][32 + lg * 8];

  f32x4 o0 = {}, o1 = {}, o2 = {}, o3 = {};
  float mrow[4], lrow[4];
#pragma unroll
  for (int j = 0; j < 4; ++j) { mrow[j] = -1e30f; lrow[j] = 0.f; }

  for (int t = 0; t < NKT; ++t) {
    int k0 = t * 64;
    __syncthreads();   // Vs consumed by prev iter's PV; tables ready (t=0)

    // ---- stage V tile transposed: Vs[d][k] ----
    {
      int kr = tid >> 3, d0 = (tid & 7) * 8;
#pragma unroll
      for (int rep = 0; rep < 2; ++rep) {
        int krl = kr + rep * 32;
        int key = min(k0 + krl, NOUT - 1);
        bf16x8 v = *(const bf16x8*)(V + base + (size_t)key * DH + d0);
#pragma unroll
        for (int i = 0; i < 8; ++i) Vs[d0 + i][krl] = (u16)v[i];
      }
    }
    __syncthreads();

    // ---- S = scale*Q.K^T + bias, per 16-key subtile ----
    f32x4 s[4];
#pragma unroll
    for (int sub = 0; sub < 4; ++sub) {
      int key = k0 + sub * 16 + l15;
      int keff = min(key, NOUT - 1);
      const u16* kp = K + base + (size_t)keff * DH + lg * 8;
      bf16x8 kb0 = *(const bf16x8*)(kp);
      bf16x8 kb1 = *(const bf16x8*)(kp + 32);
      f32x4 acc = {};
      acc = __builtin_amdgcn_mfma_f32_16x16x32_bf16(qa0, kb0, acc, 0, 0, 0);
      acc = __builtin_amdgcn_mfma_f32_16x16x32_bf16(qa1, kb1, acc, 0, 0, 0);
      bool kv = key < NOUT;
      int km1 = key - 1;
      int ky = km1 / HO, kx = km1 % HO;   // valid when key>=1
#pragma unroll
      for (int j = 0; j < 4; ++j) {
        float v = acc[j] * 0.125f;
        if (key >= 1 && kv) {
          int ql = w * 16 + lg * 4 + j;
          v += relh[ql][ky] + relw[ql][kx];   // zero rows handle qi==0
        }
        if (!kv) v = -1e30f;
        s[sub][j] = v;
      }
    }

    // ---- online softmax update (row = query; reduce over lane&15) ----
    float alpha[4];
#pragma unroll
    for (int j = 0; j < 4; ++j) {
      float lm = fmaxf(fmaxf(s[0][j], s[1][j]), fmaxf(s[2][j], s[3][j]));
      lm = fmaxf(lm, __shfl_xor(lm, 1));
      lm = fmaxf(lm, __shfl_xor(lm, 2));
      lm = fmaxf(lm, __shfl_xor(lm, 4));
      lm = fmaxf(lm, __shfl_xor(lm, 8));
      float mnew = fmaxf(mrow[j], lm);
      alpha[j] = __expf(mrow[j] - mnew);
      mrow[j] = mnew;
      float ps = 0.f;
#pragma unroll
      for (int sub = 0; sub < 4; ++sub) {
        float pv = __expf(s[sub][j] - mnew);
        s[sub][j] = pv;
        ps += pv;
      }
      ps += __shfl_xor(ps, 1);
      ps += __shfl_xor(ps, 2);
      ps += __shfl_xor(ps, 4);
      ps += __shfl_xor(ps, 8);
      lrow[j] = lrow[j] * alpha[j] + ps;
    }

    // ---- rescale O, bounce P to LDS (bf16, A-layout re-org) ----
#pragma unroll
    for (int j = 0; j < 4; ++j) {
      o0[j] *= alpha[j]; o1[j] *= alpha[j]; o2[j] *= alpha[j]; o3[j] *= alpha[j];
      Ps[w][lg * 4 + j][ 0 + l15] = f2b(s[0][j]);
      Ps[w][lg * 4 + j][16 + l15] = f2b(s[1][j]);
      Ps[w][lg * 4 + j][32 + l15] = f2b(s[2][j]);
      Ps[w][lg * 4 + j][48 + l15] = f2b(s[3][j]);
    }

    // ---- O += P.V ----
    bf16x8 pa0 = *(const bf16x8*)&Ps[w][l15][lg * 8];
    bf16x8 pa1 = *(const bf16x8*)&Ps[w][l15][32 + lg * 8];
    {
      bf16x8 vb0 = *(const bf16x8*)&Vs[ 0 + l15][lg * 8];
      bf16x8 vb1 = *(const bf16x8*)&Vs[ 0 + l15][32 + lg * 8];
      o0 = __builtin_amdgcn_mfma_f32_16x16x32_bf16(pa0, vb0, o0, 0, 0, 0);
      o0 = __builtin_amdgcn_mfma_f32_16x16x32_bf16(pa1, vb1, o0, 0, 0, 0);
    }
    {
      bf16x8 vb0 = *(const bf16x8*)&Vs[16 + l15][lg * 8];
      bf16x8 vb1 = *(const bf16x8*)&Vs[16 + l15][32 + lg * 8];
      o1 = __builtin_amdgcn_mfma_f32_16x16x32_bf16(pa0, vb0, o1, 0, 0, 0);
      o1 = __builtin_amdgcn_mfma_f32_16x16x32_bf16(pa1, vb1, o1, 0, 0, 0);
    }
    {
      bf16x8 vb0 = *(const bf16x8*)&Vs[32 + l15][lg * 8];
      bf16x8 vb1 = *(const bf16x8*)&Vs[32 + l15][32 + lg * 8];
      o2 = __builtin_amdgcn_mfma_f32_16x16x32_bf16(pa0, vb0, o2, 0, 0, 0);
      o2 = __builtin_amdgcn_mfma_f32_16x16x32_bf16(pa1, vb1, o2, 0, 0, 0);
    }
    {
      bf16x8 vb0 = *(const bf16x8*)&Vs[48 + l15][lg * 8];
      bf16x8 vb1 = *(const bf16x8*)&Vs[48 + l15][32 + lg * 8];
      o3 = __builtin_amdgcn_mfma_f32_16x16x32_bf16(pa0, vb0, o3, 0, 0, 0);
      o3 = __builtin_amdgcn_mfma_f32_16x16x32_bf16(pa1, vb1, o3, 0, 0, 0);
    }
  }

  // ---- epilogue: normalize, residual, store ----
  int b = bh >> 3, h = bh & 7;
#pragma unroll
  for (int j = 0; j < 4; ++j) {
    int ql = w * 16 + lg * 4 + j;
    int qi = q0 + ql;
    if (qi >= NOUT) continue;
    float inv = 1.f / lrow[j];
    float v0 = o0[j] * inv, v1 = o1[j] * inv, v2 = o2[j] * inv, v3 = o3[j] * inv;
    if (qi > 0) {
      v0 += b2f(Qs[ql][ 0 + l15]);
      v1 += b2f(Qs[ql][16 + l15]);
      v2 += b2f(Qs[ql][32 + l15]);
      v3 += b2f(Qs[ql][48 + l15]);
    }
    size_t ob = ((size_t)b * NOUT + qi) * CDIM + h * DH;
    O[ob +  0 + l15] = f2b(v0);
    O[ob + 16 + l15] = f2b(v1);
    O[ob + 32 + l15] = f2b(v2);
    O[ob + 48 + l15] = f2b(v3);
  }
}

// ---------------------------------------------------------------------------
// ws schedule unchanged from round 6 (verified):
//   pool -> ws0,ws1,ws2 ; gemm q->d_out(scratch) k->ws0 v->ws1 ;
//   attn -> ws2 ; proj -> d_out (f32)
// ---------------------------------------------------------------------------
extern "C" void kernel_launch(void* const* d_in, const int* in_sizes, int n_in,
                              void* d_out, int out_size, void* d_ws, size_t ws_size,
                              hipStream_t stream) {
  const float* x     = (const float*)d_in[0];
  const float* xr    = (const float*)d_in[1];
  const float* wq    = (const float*)d_in[2];
  const float* bq    = (const float*)d_in[3];
  const float* wk    = (const float*)d_in[4];
  const float* bk    = (const float*)d_in[5];
  const float* wv    = (const float*)d_in[6];
  const float* bv    = (const float*)d_in[7];
  const float* wpj   = (const float*)d_in[8];
  const float* bpj   = (const float*)d_in[9];
  const float* cwq   = (const float*)d_in[10];
  const float* cwk   = (const float*)d_in[11];
  const float* cwv   = (const float*)d_in[12];
  const float* gq    = (const float*)d_in[13];
  const float* lbq   = (const float*)d_in[14];
  const float* gk    = (const float*)d_in[15];
  const float* lbk   = (const float*)d_in[16];
  const float* gv    = (const float*)d_in[17];
  const float* lbv   = (const float*)d_in[18];
  const float* rph   = (const float*)d_in[19];
  const float* rpw   = (const float*)d_in[20];
  (void)in_sizes; (void)n_in; (void)out_size; (void)ws_size;

  u16* ws = (u16*)d_ws;
  const size_t PSZ = (size_t)ROWS * CDIM;
  u16* ws0 = ws + 0 * PSZ;
  u16* ws1 = ws + 1 * PSZ;
  u16* ws2 = ws + 2 * PSZ;
  u16* qbuf = (u16*)d_out;   // bf16 scratch inside the f32 output buffer

  pool_ln_kernel<<<dim3(NOUT, 64, 3), 64, 0, stream>>>(
      x, xr, cwq, cwk, cwv, gq, lbq, gk, lbk, gv, lbv, ws0, ws1, ws2);

  dim3 ggrid((ROWS + 63) / 64, CDIM / 64);
  gemm_kernel<<<ggrid, 256, 0, stream>>>(ws0, wq, bq, qbuf, nullptr, ROWS, 1);
  gemm_kernel<<<ggrid, 256, 0, stream>>>(ws1, wk, bk, ws0,  nullptr, ROWS, 1);
  gemm_kernel<<<ggrid, 256, 0, stream>>>(ws2, wv, bv, ws1,  nullptr, ROWS, 1);

  fattn_kernel<<<dim3(NKT, 64), 256, 0, stream>>>(qbuf, ws0, ws1, rph, rpw, ws2);

  gemm_kernel<<<ggrid, 256, 0, stream>>>(ws2, wpj, bpj, nullptr, (float*)d_out, ROWS, 2);
}

// Round 8
// 349.439 us; speedup vs baseline: 9.1972x; 1.8173x over previous
//
#include <hip/hip_runtime.h>

// Problem constants (B=8, T=1, H=56, C=512, nh=8, d=64)
// Inputs: float32. Output: float32. ws intermediates: bf16.
#define NH    8
#define DH    64
#define NTOK  3137      // 56*56+1
#define NOUT  785       // 28*28+1
#define CDIM  512
#define ROWS  6280      // 8*785
#define HO    28
#define HIN   56
#define NKT   13        // ceil(785/64) key tiles

typedef unsigned short u16;
typedef __attribute__((ext_vector_type(8))) short bf16x8;   // 8 bf16 = 4 VGPRs
typedef __attribute__((ext_vector_type(4))) float f32x4;    // MFMA C/D

__device__ __forceinline__ float b2f(u16 u) { return __uint_as_float(((unsigned)u) << 16); }
__device__ __forceinline__ u16 f2b(float f) {
  unsigned u = __float_as_uint(f);
  return (u16)((u + 0x7FFFu + ((u >> 16) & 1u)) >> 16);
}

// ---------------------------------------------------------------------------
// Kernel 1: depthwise 3x3 stride-2 pool + LayerNorm(64) (unchanged, verified)
// ---------------------------------------------------------------------------
__global__ __launch_bounds__(64) void pool_ln_kernel(
    const float* __restrict__ x, const float* __restrict__ xr,
    const float* __restrict__ cwq, const float* __restrict__ cwk, const float* __restrict__ cwv,
    const float* __restrict__ gq, const float* __restrict__ bq,
    const float* __restrict__ gk, const float* __restrict__ bk,
    const float* __restrict__ gv, const float* __restrict__ bv,
    u16* __restrict__ Pq, u16* __restrict__ Pk, u16* __restrict__ Pv)
{
  int n     = blockIdx.x;
  int bh    = blockIdx.y;
  int which = blockIdx.z;
  int b = bh >> 3, h = bh & 7;
  int di = threadIdx.x;

  const float* src = (which == 0) ? x : xr;
  const float* cw  = (which == 0) ? cwq : (which == 1 ? cwk : cwv);
  const float* g   = (which == 0) ? gq  : (which == 1 ? gk  : gv);
  const float* be  = (which == 0) ? bq  : (which == 1 ? bk  : bv);
  u16* P           = (which == 0) ? Pq  : (which == 1 ? Pk  : Pv);

  size_t srcbase = (size_t)b * NTOK * CDIM + (size_t)h * DH + di;

  float val;
  if (n == 0) {
    val = src[srcbase];
  } else {
    int oy = (n - 1) / HO, ox = (n - 1) % HO;
    float acc = 0.f;
#pragma unroll
    for (int ky = 0; ky < 3; ++ky) {
      int iy = oy * 2 - 1 + ky;
      if (iy < 0 || iy >= HIN) continue;
#pragma unroll
      for (int kx = 0; kx < 3; ++kx) {
        int ix = ox * 2 - 1 + kx;
        if (ix < 0 || ix >= HIN) continue;
        int tok = 1 + iy * HIN + ix;
        acc += src[srcbase + (size_t)tok * CDIM] * cw[(ky * 3 + kx) * DH + di];
      }
    }
    val = acc;
  }

  float s = val, sq = val * val;
#pragma unroll
  for (int off = 32; off > 0; off >>= 1) {
    s  += __shfl_xor(s, off, 64);
    sq += __shfl_xor(sq, off, 64);
  }
  float mu  = s * (1.f / 64.f);
  float var = sq * (1.f / 64.f) - mu * mu;
  float o = (val - mu) * rsqrtf(var + 1e-5f) * g[di] + be[di];

  P[(size_t)(b * NOUT + n) * CDIM + h * DH + di] = f2b(o);
}

// ---------------------------------------------------------------------------
// Kernel 2: convert the four 512x512 f32 weight matrices to bf16 (packed).
// ---------------------------------------------------------------------------
__global__ __launch_bounds__(256) void wcvt_kernel(
    const float* __restrict__ W0, const float* __restrict__ W1,
    const float* __restrict__ W2, const float* __restrict__ W3,
    u16* __restrict__ out)
{
  int idx = blockIdx.x * blockDim.x + threadIdx.x;   // one float4 per thread
  const int per = CDIM * CDIM / 4;                   // 65536
  int mat = idx / per, off = (idx - mat * per) * 4;
  const float* src = (mat == 0) ? W0 : (mat == 1) ? W1 : (mat == 2) ? W2 : W3;
  float4 v = *(const float4*)(src + off);
  ushort4 o;
  o.x = f2b(v.x); o.y = f2b(v.y); o.z = f2b(v.z); o.w = f2b(v.w);
  *(ushort4*)(out + (size_t)mat * (CDIM * CDIM) + off) = o;
}

// ---------------------------------------------------------------------------
// Kernel 3: MFMA GEMM.  Y[r,co] = sum_ci X[r,ci]*Wb[co,ci] + bias[co]
// X bf16 (ROWS x 512), Wb bf16 (512 x 512), bias f32.
// Direct-from-global fragments (all operands L2-resident), no LDS.
// Block 256 thr = 4 waves (2x2), tile 128x128, wave 64x64, K-chunk 32.
// mode 1: bf16 scatter into (b,h,n,d);  mode 2: f32 row-major.
// ---------------------------------------------------------------------------
__global__ __launch_bounds__(256) void mgemm_kernel(
    const u16* __restrict__ X, const u16* __restrict__ Wb, const float* __restrict__ bias,
    u16* __restrict__ Yb16, float* __restrict__ Yf32, int R, int mode)
{
  int tid = threadIdx.x;
  int w = tid >> 6, lane = tid & 63, l15 = lane & 15, lg = lane >> 4;
  int m0 = blockIdx.x * 128 + (w >> 1) * 64;
  int n0 = blockIdx.y * 128 + (w & 1) * 64;

  f32x4 acc[4][4] = {};
  float bs[4];
#pragma unroll
  for (int nf = 0; nf < 4; ++nf) bs[nf] = bias[n0 + nf * 16 + l15];

  for (int k0 = 0; k0 < CDIM; k0 += 32) {
    bf16x8 a[4], b[4];
#pragma unroll
    for (int mf = 0; mf < 4; ++mf) {
      int r = m0 + mf * 16 + l15;
      if (r > R - 1) r = R - 1;
      a[mf] = *(const bf16x8*)(X + (size_t)r * CDIM + k0 + lg * 8);
    }
#pragma unroll
    for (int nf = 0; nf < 4; ++nf) {
      int co = n0 + nf * 16 + l15;
      b[nf] = *(const bf16x8*)(Wb + (size_t)co * CDIM + k0 + lg * 8);
    }
#pragma unroll
    for (int mf = 0; mf < 4; ++mf)
#pragma unroll
      for (int nf = 0; nf < 4; ++nf)
        acc[mf][nf] = __builtin_amdgcn_mfma_f32_16x16x32_bf16(a[mf], b[nf], acc[mf][nf], 0, 0, 0);
  }

#pragma unroll
  for (int mf = 0; mf < 4; ++mf) {
#pragma unroll
    for (int j = 0; j < 4; ++j) {
      int r = m0 + mf * 16 + lg * 4 + j;
      if (r >= R) continue;
      int bb = r / NOUT, n = r % NOUT;
#pragma unroll
      for (int nf = 0; nf < 4; ++nf) {
        int co = n0 + nf * 16 + l15;
        float v = acc[mf][nf][j] + bs[nf];
        if (mode == 1) {
          Yb16[(((size_t)bb * NH + (co >> 6)) * NOUT + n) * DH + (co & 63)] = f2b(v);
        } else {
          Yf32[(size_t)r * CDIM + co] = v;
        }
      }
    }
  }
}

// ---------------------------------------------------------------------------
// Kernel 4: rel-pos bias tables.  Th[bh][qi][kc] = r_q . Rh[qy-kc+27],
// Tw likewise with qx. Row qi=0 is zeros. bf16 output.
// Grid (13 qtiles, 64 bh), 256 threads.
// ---------------------------------------------------------------------------
__global__ __launch_bounds__(256) void relpos_kernel(
    const u16* __restrict__ Q, const float* __restrict__ rph, const float* __restrict__ rpw,
    u16* __restrict__ Th, u16* __restrict__ Tw)
{
  __shared__ float Qsf[64][65];
  int tid = threadIdx.x;
  int qt = blockIdx.x, bh = blockIdx.y;
  int q0 = qt * 64;
  size_t base = (size_t)bh * NOUT * DH;

  {
    int q = tid >> 2, d0 = (tid & 3) * 16;
    int qi = min(q0 + q, NOUT - 1);
    const u16* src = Q + base + (size_t)qi * DH + d0;
#pragma unroll
    for (int i = 0; i < 16; ++i) Qsf[q][d0 + i] = b2f(src[i]);
  }
  __syncthreads();

  for (int idx = tid; idx < 64 * 28; idx += 256) {
    int q = idx / 28, kc = idx % 28;
    int qi = q0 + q;
    if (qi >= NOUT) continue;
    float vh = 0.f, vw = 0.f;
    if (qi >= 1) {
      int qy = (qi - 1) / HO, qx = (qi - 1) % HO;
      const float* rh = rph + (size_t)(qy - kc + 27) * DH;
      const float* rw = rpw + (size_t)(qx - kc + 27) * DH;
      for (int d = 0; d < DH; ++d) {
        float qv = Qsf[q][d];
        vh += qv * rh[d];
        vw += qv * rw[d];
      }
    }
    Th[((size_t)bh * NOUT + qi) * 28 + kc] = f2b(vh);
    Tw[((size_t)bh * NOUT + qi) * 28 + kc] = f2b(vw);
  }
}

// ---------------------------------------------------------------------------
// Kernel 5: flash-style MFMA attention (tables precomputed; swizzled V tile).
// Block = 4 waves; one block per (bh, 64-query tile); keys in tiles of 64.
// Vs layout: row d (64 u16/row), key col-block XOR-swizzled: blk = (k>>3)^(d&7).
// ---------------------------------------------------------------------------
__global__ __launch_bounds__(256) void fattn_kernel(
    const u16* __restrict__ Q, const u16* __restrict__ K, const u16* __restrict__ V,
    const u16* __restrict__ Th, const u16* __restrict__ Tw,
    u16* __restrict__ O)
{
  __shared__ u16 Qs[64][72];       // [q][d]
  __shared__ u16 Vs[64][64];       // [d][k] XOR-swizzled
  __shared__ u16 Ps[4][16][72];    // per-wave P bounce
  __shared__ u16 relh[64][28];
  __shared__ u16 relw[64][28];

  int tid = threadIdx.x;
  int qt = blockIdx.x, bh = blockIdx.y;
  int w = tid >> 6, lane = tid & 63, l15 = lane & 15, lg = lane >> 4;
  size_t base = (size_t)bh * NOUT * DH;
  int q0 = qt * 64;

  // ---- stage Q tile ----
  {
    int q = tid >> 2, d0 = (tid & 3) * 16;
    int qi = min(q0 + q, NOUT - 1);
    const u16* src = Q + base + (size_t)qi * DH + d0;
    bf16x8 a = *(const bf16x8*)(src);
    bf16x8 b = *(const bf16x8*)(src + 8);
    *(bf16x8*)&Qs[q][d0]     = a;
    *(bf16x8*)&Qs[q][d0 + 8] = b;
  }

  // ---- stage rel-pos table rows (coalesced copy) ----
  for (int idx = tid; idx < 64 * 28; idx += 256) {
    int q = idx / 28, kc = idx % 28;
    int qi = min(q0 + q, NOUT - 1);
    relh[q][kc] = Th[((size_t)bh * NOUT + qi) * 28 + kc];
    relw[q][kc] = Tw[((size_t)bh * NOUT + qi) * 28 + kc];
  }
  __syncthreads();

  // ---- Q A-fragments ----
  int qrow = w * 16 + l15;
  bf16x8 qa0 = *(const bf16x8*)&Qs[qrow][lg * 8];
  bf16x8 qa1 = *(const bf16x8*)&Qs[qrow][32 + lg * 8];

  f32x4 o0 = {}, o1 = {}, o2 = {}, o3 = {};
  float mrow[4], lrow[4];
#pragma unroll
  for (int j = 0; j < 4; ++j) { mrow[j] = -1e30f; lrow[j] = 0.f; }

  for (int t = 0; t < NKT; ++t) {
    int k0 = t * 64;
    __syncthreads();   // Vs consumed by prev iter's PV

    // ---- stage V tile transposed+swizzled: lane <-> key (conflict-free) ----
    {
      int key_l = tid & 63;
      int d0 = (tid >> 6) * 16;
      int key = min(k0 + key_l, NOUT - 1);
      const u16* vp = V + base + (size_t)key * DH + d0;
      bf16x8 v0 = *(const bf16x8*)(vp);
      bf16x8 v1 = *(const bf16x8*)(vp + 8);
#pragma unroll
      for (int i = 0; i < 8; ++i) {
        int d = d0 + i;
        Vs[d][((((key_l >> 3) ^ (d & 7)) << 3) | (key_l & 7))] = (u16)v0[i];
      }
#pragma unroll
      for (int i = 0; i < 8; ++i) {
        int d = d0 + 8 + i;
        Vs[d][((((key_l >> 3) ^ (d & 7)) << 3) | (key_l & 7))] = (u16)v1[i];
      }
    }
    __syncthreads();

    // ---- S = scale*Q.K^T + bias ----
    f32x4 s[4];
#pragma unroll
    for (int sub = 0; sub < 4; ++sub) {
      int key = k0 + sub * 16 + l15;
      int keff = min(key, NOUT - 1);
      const u16* kp = K + base + (size_t)keff * DH + lg * 8;
      bf16x8 kb0 = *(const bf16x8*)(kp);
      bf16x8 kb1 = *(const bf16x8*)(kp + 32);
      f32x4 acc = {};
      acc = __builtin_amdgcn_mfma_f32_16x16x32_bf16(qa0, kb0, acc, 0, 0, 0);
      acc = __builtin_amdgcn_mfma_f32_16x16x32_bf16(qa1, kb1, acc, 0, 0, 0);
      bool kv = key < NOUT;
      int km1 = key - 1;
      int ky = km1 / HO, kx = km1 % HO;
#pragma unroll
      for (int j = 0; j < 4; ++j) {
        float v = acc[j] * 0.125f;
        if (key >= 1 && kv) {
          int ql = w * 16 + lg * 4 + j;
          v += b2f(relh[ql][ky]) + b2f(relw[ql][kx]);
        }
        if (!kv) v = -1e30f;
        s[sub][j] = v;
      }
    }

    // ---- online softmax ----
    float alpha[4];
#pragma unroll
    for (int j = 0; j < 4; ++j) {
      float lm = fmaxf(fmaxf(s[0][j], s[1][j]), fmaxf(s[2][j], s[3][j]));
      lm = fmaxf(lm, __shfl_xor(lm, 1));
      lm = fmaxf(lm, __shfl_xor(lm, 2));
      lm = fmaxf(lm, __shfl_xor(lm, 4));
      lm = fmaxf(lm, __shfl_xor(lm, 8));
      float mnew = fmaxf(mrow[j], lm);
      alpha[j] = __expf(mrow[j] - mnew);
      mrow[j] = mnew;
      float ps = 0.f;
#pragma unroll
      for (int sub = 0; sub < 4; ++sub) {
        float pv = __expf(s[sub][j] - mnew);
        s[sub][j] = pv;
        ps += pv;
      }
      ps += __shfl_xor(ps, 1);
      ps += __shfl_xor(ps, 2);
      ps += __shfl_xor(ps, 4);
      ps += __shfl_xor(ps, 8);
      lrow[j] = lrow[j] * alpha[j] + ps;
    }

    // ---- rescale O, bounce P ----
#pragma unroll
    for (int j = 0; j < 4; ++j) {
      o0[j] *= alpha[j]; o1[j] *= alpha[j]; o2[j] *= alpha[j]; o3[j] *= alpha[j];
      Ps[w][lg * 4 + j][ 0 + l15] = f2b(s[0][j]);
      Ps[w][lg * 4 + j][16 + l15] = f2b(s[1][j]);
      Ps[w][lg * 4 + j][32 + l15] = f2b(s[2][j]);
      Ps[w][lg * 4 + j][48 + l15] = f2b(s[3][j]);
    }

    // ---- O += P.V (Vs read: row r, key-block kb stored at kb^(r&7)) ----
    bf16x8 pa0 = *(const bf16x8*)&Ps[w][l15][lg * 8];
    bf16x8 pa1 = *(const bf16x8*)&Ps[w][l15][32 + lg * 8];
    {
      int r = 0 + l15;
      bf16x8 vb0 = *(const bf16x8*)&Vs[r][((lg ^ (r & 7)) << 3)];
      bf16x8 vb1 = *(const bf16x8*)&Vs[r][(((4 + lg) ^ (r & 7)) << 3)];
      o0 = __builtin_amdgcn_mfma_f32_16x16x32_bf16(pa0, vb0, o0, 0, 0, 0);
      o0 = __builtin_amdgcn_mfma_f32_16x16x32_bf16(pa1, vb1, o0, 0, 0, 0);
    }
    {
      int r = 16 + l15;
      bf16x8 vb0 = *(const bf16x8*)&Vs[r][((lg ^ (r & 7)) << 3)];
      bf16x8 vb1 = *(const bf16x8*)&Vs[r][(((4 + lg) ^ (r & 7)) << 3)];
      o1 = __builtin_amdgcn_mfma_f32_16x16x32_bf16(pa0, vb0, o1, 0, 0, 0);
      o1 = __builtin_amdgcn_mfma_f32_16x16x32_bf16(pa1, vb1, o1, 0, 0, 0);
    }
    {
      int r = 32 + l15;
      bf16x8 vb0 = *(const bf16x8*)&Vs[r][((lg ^ (r & 7)) << 3)];
      bf16x8 vb1 = *(const bf16x8*)&Vs[r][(((4 + lg) ^ (r & 7)) << 3)];
      o2 = __builtin_amdgcn_mfma_f32_16x16x32_bf16(pa0, vb0, o2, 0, 0, 0);
      o2 = __builtin_amdgcn_mfma_f32_16x16x32_bf16(pa1, vb1, o2, 0, 0, 0);
    }
    {
      int r = 48 + l15;
      bf16x8 vb0 = *(const bf16x8*)&Vs[r][((lg ^ (r & 7)) << 3)];
      bf16x8 vb1 = *(const bf16x8*)&Vs[r][(((4 + lg) ^ (r & 7)) << 3)];
      o3 = __builtin_amdgcn_mfma_f32_16x16x32_bf16(pa0, vb0, o3, 0, 0, 0);
      o3 = __builtin_amdgcn_mfma_f32_16x16x32_bf16(pa1, vb1, o3, 0, 0, 0);
    }
  }

  // ---- epilogue ----
  int b = bh >> 3, h = bh & 7;
#pragma unroll
  for (int j = 0; j < 4; ++j) {
    int ql = w * 16 + lg * 4 + j;
    int qi = q0 + ql;
    if (qi >= NOUT) continue;
    float inv = 1.f / lrow[j];
    float v0 = o0[j] * inv, v1 = o1[j] * inv, v2 = o2[j] * inv, v3 = o3[j] * inv;
    if (qi > 0) {
      v0 += b2f(Qs[ql][ 0 + l15]);
      v1 += b2f(Qs[ql][16 + l15]);
      v2 += b2f(Qs[ql][32 + l15]);
      v3 += b2f(Qs[ql][48 + l15]);
    }
    size_t ob = ((size_t)b * NOUT + qi) * CDIM + h * DH;
    O[ob +  0 + l15] = f2b(v0);
    O[ob + 16 + l15] = f2b(v1);
    O[ob + 32 + l15] = f2b(v2);
    O[ob + 48 + l15] = f2b(v3);
  }
}

// ---------------------------------------------------------------------------
// ws layout (u16 units):
//   ws0/ws1/ws2: 3 x PSZ (P/QKV/O bounce, schedule as round 6)
//   Wb[4]     : 4 x 512*512  (bf16 weights: q,k,v,proj)
//   Th, Tw    : 2 x 64*785*28 (rel-pos tables)
// Total ~27 MB.
// ---------------------------------------------------------------------------
extern "C" void kernel_launch(void* const* d_in, const int* in_sizes, int n_in,
                              void* d_out, int out_size, void* d_ws, size_t ws_size,
                              hipStream_t stream) {
  const float* x     = (const float*)d_in[0];
  const float* xr    = (const float*)d_in[1];
  const float* wq    = (const float*)d_in[2];
  const float* bq    = (const float*)d_in[3];
  const float* wk    = (const float*)d_in[4];
  const float* bk    = (const float*)d_in[5];
  const float* wv    = (const float*)d_in[6];
  const float* bv    = (const float*)d_in[7];
  const float* wpj   = (const float*)d_in[8];
  const float* bpj   = (const float*)d_in[9];
  const float* cwq   = (const float*)d_in[10];
  const float* cwk   = (const float*)d_in[11];
  const float* cwv   = (const float*)d_in[12];
  const float* gq    = (const float*)d_in[13];
  const float* lbq   = (const float*)d_in[14];
  const float* gk    = (const float*)d_in[15];
  const float* lbk   = (const float*)d_in[16];
  const float* gv    = (const float*)d_in[17];
  const float* lbv   = (const float*)d_in[18];
  const float* rph   = (const float*)d_in[19];
  const float* rpw   = (const float*)d_in[20];
  (void)in_sizes; (void)n_in; (void)out_size; (void)ws_size;

  u16* ws = (u16*)d_ws;
  const size_t PSZ = (size_t)ROWS * CDIM;
  const size_t WSZ = (size_t)CDIM * CDIM;
  const size_t TSZ = (size_t)64 * NOUT * 28;
  u16* ws0 = ws + 0 * PSZ;
  u16* ws1 = ws + 1 * PSZ;
  u16* ws2 = ws + 2 * PSZ;
  u16* Wb  = ws + 3 * PSZ;              // 4 matrices
  u16* Th  = ws + 3 * PSZ + 4 * WSZ;
  u16* Tw  = Th + TSZ;
  u16* qbuf = (u16*)d_out;              // bf16 scratch inside f32 output buffer

  // 1) pool + layernorm
  pool_ln_kernel<<<dim3(NOUT, 64, 3), 64, 0, stream>>>(
      x, xr, cwq, cwk, cwv, gq, lbq, gk, lbk, gv, lbv, ws0, ws1, ws2);

  // 2) weights -> bf16
  wcvt_kernel<<<(4 * CDIM * CDIM / 4 + 255) / 256, 256, 0, stream>>>(wq, wk, wv, wpj, Wb);

  // 3) q/k/v linear projections (MFMA) -> (b,h,n,d) bf16
  dim3 ggrid((ROWS + 127) / 128, CDIM / 128);
  mgemm_kernel<<<ggrid, 256, 0, stream>>>(ws0, Wb + 0 * WSZ, bq, qbuf, nullptr, ROWS, 1);
  mgemm_kernel<<<ggrid, 256, 0, stream>>>(ws1, Wb + 1 * WSZ, bk, ws0,  nullptr, ROWS, 1);
  mgemm_kernel<<<ggrid, 256, 0, stream>>>(ws2, Wb + 2 * WSZ, bv, ws1,  nullptr, ROWS, 1);

  // 4) rel-pos tables from Q
  relpos_kernel<<<dim3(NKT, 64), 256, 0, stream>>>(qbuf, rph, rpw, Th, Tw);

  // 5) attention -> ws2
  fattn_kernel<<<dim3(NKT, 64), 256, 0, stream>>>(qbuf, ws0, ws1, Th, Tw, ws2);

  // 6) output projection (MFMA) -> f32 d_out
  mgemm_kernel<<<ggrid, 256, 0, stream>>>(ws2, Wb + 3 * WSZ, bpj, nullptr, (float*)d_out, ROWS, 2);
}

// Round 9
// 265.810 us; speedup vs baseline: 12.0909x; 1.3146x over previous
//
#include <hip/hip_runtime.h>

// Problem constants (B=8, T=1, H=56, C=512, nh=8, d=64)
// Inputs: float32. Output: float32. ws intermediates: bf16.
#define NH    8
#define DH    64
#define NTOK  3137      // 56*56+1
#define NOUT  785       // 28*28+1
#define CDIM  512
#define ROWS  6280      // 8*785
#define HO    28
#define HIN   56
#define NKT   13        // ceil(785/64) key tiles
#define RELD  55        // 2*(56//2)-1

typedef unsigned short u16;
typedef __attribute__((ext_vector_type(8))) short bf16x8;   // 8 bf16 = 4 VGPRs
typedef __attribute__((ext_vector_type(4))) float f32x4;    // MFMA C/D

__device__ __forceinline__ float b2f(u16 u) { return __uint_as_float(((unsigned)u) << 16); }
__device__ __forceinline__ u16 f2b(float f) {
  unsigned u = __float_as_uint(f);
  return (u16)((u + 0x7FFFu + ((u >> 16) & 1u)) >> 16);
}

// ---------------------------------------------------------------------------
// Kernel 1: depthwise 3x3 stride-2 pool + LayerNorm(64).
// z=0: q from x.  z=1: k AND v from x_ref (one pass, shared conv reads).
// ---------------------------------------------------------------------------
__global__ __launch_bounds__(64) void pool_ln_kernel(
    const float* __restrict__ x, const float* __restrict__ xr,
    const float* __restrict__ cwq, const float* __restrict__ cwk, const float* __restrict__ cwv,
    const float* __restrict__ gq, const float* __restrict__ bq,
    const float* __restrict__ gk, const float* __restrict__ bk,
    const float* __restrict__ gv, const float* __restrict__ bv,
    u16* __restrict__ Pq, u16* __restrict__ Pk, u16* __restrict__ Pv)
{
  int n     = blockIdx.x;       // 0..784
  int bh    = blockIdx.y;       // b*8 + h
  int which = blockIdx.z;       // 0=q(x), 1=k+v(x_ref)
  int b = bh >> 3, h = bh & 7;
  int di = threadIdx.x;

  const float* src = (which == 0) ? x : xr;
  size_t srcbase = (size_t)b * NTOK * CDIM + (size_t)h * DH + di;
  size_t obase = (size_t)(b * NOUT + n) * CDIM + h * DH + di;

  float vq = 0.f, vk = 0.f;   // which==0: vq only; which==1: vq->k acc, vk->v acc
  const float* cw0 = (which == 0) ? cwq : cwk;

  if (n == 0) {
    float t = src[srcbase];
    vq = t; vk = t;
  } else {
    int oy = (n - 1) / HO, ox = (n - 1) % HO;
#pragma unroll
    for (int ky = 0; ky < 3; ++ky) {
      int iy = oy * 2 - 1 + ky;
      if (iy < 0 || iy >= HIN) continue;
#pragma unroll
      for (int kx = 0; kx < 3; ++kx) {
        int ix = ox * 2 - 1 + kx;
        if (ix < 0 || ix >= HIN) continue;
        int tok = 1 + iy * HIN + ix;
        float t = src[srcbase + (size_t)tok * CDIM];
        vq += t * cw0[(ky * 3 + kx) * DH + di];
        if (which == 1) vk += t * cwv[(ky * 3 + kx) * DH + di];
      }
    }
  }

  // LN for first output
  {
    float s = vq, sq = vq * vq;
#pragma unroll
    for (int off = 32; off > 0; off >>= 1) {
      s  += __shfl_xor(s, off, 64);
      sq += __shfl_xor(sq, off, 64);
    }
    float mu  = s * (1.f / 64.f);
    float var = sq * (1.f / 64.f) - mu * mu;
    const float* g  = (which == 0) ? gq : gk;
    const float* be = (which == 0) ? bq : bk;
    float o = (vq - mu) * rsqrtf(var + 1e-5f) * g[di] + be[di];
    ((which == 0) ? Pq : Pk)[obase] = f2b(o);
  }
  // LN for v (which==1 only)
  if (which == 1) {
    float s = vk, sq = vk * vk;
#pragma unroll
    for (int off = 32; off > 0; off >>= 1) {
      s  += __shfl_xor(s, off, 64);
      sq += __shfl_xor(sq, off, 64);
    }
    float mu  = s * (1.f / 64.f);
    float var = sq * (1.f / 64.f) - mu * mu;
    float o = (vk - mu) * rsqrtf(var + 1e-5f) * gv[di] + bv[di];
    Pv[obase] = f2b(o);
  }
}

// ---------------------------------------------------------------------------
// Kernel 2: convert the four 512x512 f32 weight matrices to bf16 (packed).
// ---------------------------------------------------------------------------
__global__ __launch_bounds__(256) void wcvt_kernel(
    const float* __restrict__ W0, const float* __restrict__ W1,
    const float* __restrict__ W2, const float* __restrict__ W3,
    u16* __restrict__ out)
{
  int idx = blockIdx.x * blockDim.x + threadIdx.x;   // one float4 per thread
  const int per = CDIM * CDIM / 4;                   // 65536
  int mat = idx / per, off = (idx - mat * per) * 4;
  const float* src = (mat == 0) ? W0 : (mat == 1) ? W1 : (mat == 2) ? W2 : W3;
  float4 v = *(const float4*)(src + off);
  ushort4 o;
  o.x = f2b(v.x); o.y = f2b(v.y); o.z = f2b(v.z); o.w = f2b(v.w);
  *(ushort4*)(out + (size_t)mat * (CDIM * CDIM) + off) = o;
}

// ---------------------------------------------------------------------------
// Kernel 3: rel_pos f32 (55x64) -> bf16 padded [64][64] (rows >=55 zero).
// ---------------------------------------------------------------------------
__global__ __launch_bounds__(256) void rcvt_kernel(
    const float* __restrict__ rph, const float* __restrict__ rpw,
    u16* __restrict__ Rhb, u16* __restrict__ Rwb)
{
  int idx = blockIdx.x * blockDim.x + threadIdx.x;   // 0..4095
  if (idx >= 64 * 64) return;
  int r = idx >> 6, d = idx & 63;
  Rhb[idx] = (r < RELD) ? f2b(rph[r * DH + d]) : 0;
  Rwb[idx] = (r < RELD) ? f2b(rpw[r * DH + d]) : 0;
}

// ---------------------------------------------------------------------------
// Kernel 4: MFMA GEMM (unchanged, verified round 8).
// ---------------------------------------------------------------------------
__global__ __launch_bounds__(256) void mgemm_kernel(
    const u16* __restrict__ X, const u16* __restrict__ Wb, const float* __restrict__ bias,
    u16* __restrict__ Yb16, float* __restrict__ Yf32, int R, int mode)
{
  int tid = threadIdx.x;
  int w = tid >> 6, lane = tid & 63, l15 = lane & 15, lg = lane >> 4;
  int m0 = blockIdx.x * 128 + (w >> 1) * 64;
  int n0 = blockIdx.y * 128 + (w & 1) * 64;

  f32x4 acc[4][4] = {};
  float bs[4];
#pragma unroll
  for (int nf = 0; nf < 4; ++nf) bs[nf] = bias[n0 + nf * 16 + l15];

  for (int k0 = 0; k0 < CDIM; k0 += 32) {
    bf16x8 a[4], b[4];
#pragma unroll
    for (int mf = 0; mf < 4; ++mf) {
      int r = m0 + mf * 16 + l15;
      if (r > R - 1) r = R - 1;
      a[mf] = *(const bf16x8*)(X + (size_t)r * CDIM + k0 + lg * 8);
    }
#pragma unroll
    for (int nf = 0; nf < 4; ++nf) {
      int co = n0 + nf * 16 + l15;
      b[nf] = *(const bf16x8*)(Wb + (size_t)co * CDIM + k0 + lg * 8);
    }
#pragma unroll
    for (int mf = 0; mf < 4; ++mf)
#pragma unroll
      for (int nf = 0; nf < 4; ++nf)
        acc[mf][nf] = __builtin_amdgcn_mfma_f32_16x16x32_bf16(a[mf], b[nf], acc[mf][nf], 0, 0, 0);
  }

#pragma unroll
  for (int mf = 0; mf < 4; ++mf) {
#pragma unroll
    for (int j = 0; j < 4; ++j) {
      int r = m0 + mf * 16 + lg * 4 + j;
      if (r >= R) continue;
      int bb = r / NOUT, n = r % NOUT;
#pragma unroll
      for (int nf = 0; nf < 4; ++nf) {
        int co = n0 + nf * 16 + l15;
        float v = acc[mf][nf][j] + bs[nf];
        if (mode == 1) {
          Yb16[(((size_t)bb * NH + (co >> 6)) * NOUT + n) * DH + (co & 63)] = f2b(v);
        } else {
          Yf32[(size_t)r * CDIM + co] = v;
        }
      }
    }
  }
}

// ---------------------------------------------------------------------------
// Kernel 5: flash-style MFMA attention with fused rel-pos table build.
// Prologue: G[q][r] = q . rel_pos[r] via MFMA (A-frags shared with QK^T).
// Lookup: bias(q,key) = Gh[q][qy-ky+27] + Gw[q][qx-kx+27].
// ---------------------------------------------------------------------------
__global__ __launch_bounds__(256) void fattn_kernel(
    const u16* __restrict__ Q, const u16* __restrict__ K, const u16* __restrict__ V,
    const u16* __restrict__ Rhb, const u16* __restrict__ Rwb,
    u16* __restrict__ O)
{
  __shared__ u16 Qs[64][72];       // [q][d]
  __shared__ u16 Vs[64][64];       // [d][k] XOR-swizzled
  __shared__ u16 Ps[4][16][72];    // per-wave P bounce
  __shared__ u16 relh[64][68];     // G_h[q][r], r<64 valid
  __shared__ u16 relw[64][68];     // G_w[q][r]

  int tid = threadIdx.x;
  int qt = blockIdx.x, bh = blockIdx.y;
  int w = tid >> 6, lane = tid & 63, l15 = lane & 15, lg = lane >> 4;
  size_t base = (size_t)bh * NOUT * DH;
  int q0 = qt * 64;

  // ---- stage Q tile ----
  {
    int q = tid >> 2, d0 = (tid & 3) * 16;
    int qi = min(q0 + q, NOUT - 1);
    const u16* src = Q + base + (size_t)qi * DH + d0;
    bf16x8 a = *(const bf16x8*)(src);
    bf16x8 b = *(const bf16x8*)(src + 8);
    *(bf16x8*)&Qs[q][d0]     = a;
    *(bf16x8*)&Qs[q][d0 + 8] = b;
  }
  __syncthreads();

  // ---- Q A-fragments ----
  int qrow = w * 16 + l15;
  bf16x8 qa0 = *(const bf16x8*)&Qs[qrow][lg * 8];
  bf16x8 qa1 = *(const bf16x8*)&Qs[qrow][32 + lg * 8];

  // ---- rel-pos tables via MFMA: rows w*16..w*16+15 of G ----
#pragma unroll
  for (int nf = 0; nf < 4; ++nf) {
    int rr = nf * 16 + l15;
    const u16* hp = Rhb + rr * 64 + lg * 8;
    bf16x8 hb0 = *(const bf16x8*)(hp);
    bf16x8 hb1 = *(const bf16x8*)(hp + 32);
    f32x4 ah = {};
    ah = __builtin_amdgcn_mfma_f32_16x16x32_bf16(qa0, hb0, ah, 0, 0, 0);
    ah = __builtin_amdgcn_mfma_f32_16x16x32_bf16(qa1, hb1, ah, 0, 0, 0);
    const u16* wp = Rwb + rr * 64 + lg * 8;
    bf16x8 wb0 = *(const bf16x8*)(wp);
    bf16x8 wb1 = *(const bf16x8*)(wp + 32);
    f32x4 aw = {};
    aw = __builtin_amdgcn_mfma_f32_16x16x32_bf16(qa0, wb0, aw, 0, 0, 0);
    aw = __builtin_amdgcn_mfma_f32_16x16x32_bf16(qa1, wb1, aw, 0, 0, 0);
#pragma unroll
    for (int j = 0; j < 4; ++j) {
      relh[w * 16 + lg * 4 + j][rr] = f2b(ah[j]);
      relw[w * 16 + lg * 4 + j][rr] = f2b(aw[j]);
    }
  }

  // ---- per-j query row geometry ----
  int qy_j[4], qx_j[4];
  bool qv_j[4];
#pragma unroll
  for (int j = 0; j < 4; ++j) {
    int qi = q0 + w * 16 + lg * 4 + j;
    qv_j[j] = (qi >= 1);
    int qm1 = qi - 1;
    qy_j[j] = qm1 / HO;
    qx_j[j] = qm1 % HO;
  }

  f32x4 o0 = {}, o1 = {}, o2 = {}, o3 = {};
  float mrow[4], lrow[4];
#pragma unroll
  for (int j = 0; j < 4; ++j) { mrow[j] = -1e30f; lrow[j] = 0.f; }

  for (int t = 0; t < NKT; ++t) {
    int k0 = t * 64;
    __syncthreads();   // Vs consumed by prev iter's PV; rel tables written (t=0)

    // ---- stage V tile transposed+swizzled (conflict-free) ----
    {
      int key_l = tid & 63;
      int d0 = (tid >> 6) * 16;
      int key = min(k0 + key_l, NOUT - 1);
      const u16* vp = V + base + (size_t)key * DH + d0;
      bf16x8 v0 = *(const bf16x8*)(vp);
      bf16x8 v1 = *(const bf16x8*)(vp + 8);
#pragma unroll
      for (int i = 0; i < 8; ++i) {
        int d = d0 + i;
        Vs[d][((((key_l >> 3) ^ (d & 7)) << 3) | (key_l & 7))] = (u16)v0[i];
      }
#pragma unroll
      for (int i = 0; i < 8; ++i) {
        int d = d0 + 8 + i;
        Vs[d][((((key_l >> 3) ^ (d & 7)) << 3) | (key_l & 7))] = (u16)v1[i];
      }
    }
    __syncthreads();

    // ---- S = scale*Q.K^T + bias ----
    f32x4 s[4];
#pragma unroll
    for (int sub = 0; sub < 4; ++sub) {
      int key = k0 + sub * 16 + l15;
      int keff = min(key, NOUT - 1);
      const u16* kp = K + base + (size_t)keff * DH + lg * 8;
      bf16x8 kb0 = *(const bf16x8*)(kp);
      bf16x8 kb1 = *(const bf16x8*)(kp + 32);
      f32x4 acc = {};
      acc = __builtin_amdgcn_mfma_f32_16x16x32_bf16(qa0, kb0, acc, 0, 0, 0);
      acc = __builtin_amdgcn_mfma_f32_16x16x32_bf16(qa1, kb1, acc, 0, 0, 0);
      bool kv = key < NOUT;
      int km1 = key - 1;
      int ky = km1 / HO, kx = km1 % HO;
#pragma unroll
      for (int j = 0; j < 4; ++j) {
        float v = acc[j] * 0.125f;
        if (key >= 1 && kv && qv_j[j]) {
          int ql = w * 16 + lg * 4 + j;
          v += b2f(relh[ql][qy_j[j] - ky + 27]) + b2f(relw[ql][qx_j[j] - kx + 27]);
        }
        if (!kv) v = -1e30f;
        s[sub][j] = v;
      }
    }

    // ---- online softmax ----
    float alpha[4];
#pragma unroll
    for (int j = 0; j < 4; ++j) {
      float lm = fmaxf(fmaxf(s[0][j], s[1][j]), fmaxf(s[2][j], s[3][j]));
      lm = fmaxf(lm, __shfl_xor(lm, 1));
      lm = fmaxf(lm, __shfl_xor(lm, 2));
      lm = fmaxf(lm, __shfl_xor(lm, 4));
      lm = fmaxf(lm, __shfl_xor(lm, 8));
      float mnew = fmaxf(mrow[j], lm);
      alpha[j] = __expf(mrow[j] - mnew);
      mrow[j] = mnew;
      float ps = 0.f;
#pragma unroll
      for (int sub = 0; sub < 4; ++sub) {
        float pv = __expf(s[sub][j] - mnew);
        s[sub][j] = pv;
        ps += pv;
      }
      ps += __shfl_xor(ps, 1);
      ps += __shfl_xor(ps, 2);
      ps += __shfl_xor(ps, 4);
      ps += __shfl_xor(ps, 8);
      lrow[j] = lrow[j] * alpha[j] + ps;
    }

    // ---- rescale O, bounce P ----
#pragma unroll
    for (int j = 0; j < 4; ++j) {
      o0[j] *= alpha[j]; o1[j] *= alpha[j]; o2[j] *= alpha[j]; o3[j] *= alpha[j];
      Ps[w][lg * 4 + j][ 0 + l15] = f2b(s[0][j]);
      Ps[w][lg * 4 + j][16 + l15] = f2b(s[1][j]);
      Ps[w][lg * 4 + j][32 + l15] = f2b(s[2][j]);
      Ps[w][lg * 4 + j][48 + l15] = f2b(s[3][j]);
    }

    // ---- O += P.V ----
    bf16x8 pa0 = *(const bf16x8*)&Ps[w][l15][lg * 8];
    bf16x8 pa1 = *(const bf16x8*)&Ps[w][l15][32 + lg * 8];
    {
      int r = 0 + l15;
      bf16x8 vb0 = *(const bf16x8*)&Vs[r][((lg ^ (r & 7)) << 3)];
      bf16x8 vb1 = *(const bf16x8*)&Vs[r][(((4 + lg) ^ (r & 7)) << 3)];
      o0 = __builtin_amdgcn_mfma_f32_16x16x32_bf16(pa0, vb0, o0, 0, 0, 0);
      o0 = __builtin_amdgcn_mfma_f32_16x16x32_bf16(pa1, vb1, o0, 0, 0, 0);
    }
    {
      int r = 16 + l15;
      bf16x8 vb0 = *(const bf16x8*)&Vs[r][((lg ^ (r & 7)) << 3)];
      bf16x8 vb1 = *(const bf16x8*)&Vs[r][(((4 + lg) ^ (r & 7)) << 3)];
      o1 = __builtin_amdgcn_mfma_f32_16x16x32_bf16(pa0, vb0, o1, 0, 0, 0);
      o1 = __builtin_amdgcn_mfma_f32_16x16x32_bf16(pa1, vb1, o1, 0, 0, 0);
    }
    {
      int r = 32 + l15;
      bf16x8 vb0 = *(const bf16x8*)&Vs[r][((lg ^ (r & 7)) << 3)];
      bf16x8 vb1 = *(const bf16x8*)&Vs[r][(((4 + lg) ^ (r & 7)) << 3)];
      o2 = __builtin_amdgcn_mfma_f32_16x16x32_bf16(pa0, vb0, o2, 0, 0, 0);
      o2 = __builtin_amdgcn_mfma_f32_16x16x32_bf16(pa1, vb1, o2, 0, 0, 0);
    }
    {
      int r = 48 + l15;
      bf16x8 vb0 = *(const bf16x8*)&Vs[r][((lg ^ (r & 7)) << 3)];
      bf16x8 vb1 = *(const bf16x8*)&Vs[r][(((4 + lg) ^ (r & 7)) << 3)];
      o3 = __builtin_amdgcn_mfma_f32_16x16x32_bf16(pa0, vb0, o3, 0, 0, 0);
      o3 = __builtin_amdgcn_mfma_f32_16x16x32_bf16(pa1, vb1, o3, 0, 0, 0);
    }
  }

  // ---- epilogue ----
  int b = bh >> 3, h = bh & 7;
#pragma unroll
  for (int j = 0; j < 4; ++j) {
    int ql = w * 16 + lg * 4 + j;
    int qi = q0 + ql;
    if (qi >= NOUT) continue;
    float inv = 1.f / lrow[j];
    float v0 = o0[j] * inv, v1 = o1[j] * inv, v2 = o2[j] * inv, v3 = o3[j] * inv;
    if (qi > 0) {
      v0 += b2f(Qs[ql][ 0 + l15]);
      v1 += b2f(Qs[ql][16 + l15]);
      v2 += b2f(Qs[ql][32 + l15]);
      v3 += b2f(Qs[ql][48 + l15]);
    }
    size_t ob = ((size_t)b * NOUT + qi) * CDIM + h * DH;
    O[ob +  0 + l15] = f2b(v0);
    O[ob + 16 + l15] = f2b(v1);
    O[ob + 32 + l15] = f2b(v2);
    O[ob + 48 + l15] = f2b(v3);
  }
}

// ---------------------------------------------------------------------------
// ws layout (u16): ws0/ws1/ws2 (3 x PSZ), Wb (4 x 512*512), Rhb/Rwb (2 x 4096).
// Schedule: pool -> ws0,ws1,ws2 ; mgemm q->d_out(scratch) k->ws0 v->ws1 ;
//           fattn -> ws2 ; mgemm proj -> d_out (f32).
// ---------------------------------------------------------------------------
extern "C" void kernel_launch(void* const* d_in, const int* in_sizes, int n_in,
                              void* d_out, int out_size, void* d_ws, size_t ws_size,
                              hipStream_t stream) {
  const float* x     = (const float*)d_in[0];
  const float* xr    = (const float*)d_in[1];
  const float* wq    = (const float*)d_in[2];
  const float* bq    = (const float*)d_in[3];
  const float* wk    = (const float*)d_in[4];
  const float* bk    = (const float*)d_in[5];
  const float* wv    = (const float*)d_in[6];
  const float* bv    = (const float*)d_in[7];
  const float* wpj   = (const float*)d_in[8];
  const float* bpj   = (const float*)d_in[9];
  const float* cwq   = (const float*)d_in[10];
  const float* cwk   = (const float*)d_in[11];
  const float* cwv   = (const float*)d_in[12];
  const float* gq    = (const float*)d_in[13];
  const float* lbq   = (const float*)d_in[14];
  const float* gk    = (const float*)d_in[15];
  const float* lbk   = (const float*)d_in[16];
  const float* gv    = (const float*)d_in[17];
  const float* lbv   = (const float*)d_in[18];
  const float* rph   = (const float*)d_in[19];
  const float* rpw   = (const float*)d_in[20];
  (void)in_sizes; (void)n_in; (void)out_size; (void)ws_size;

  u16* ws = (u16*)d_ws;
  const size_t PSZ = (size_t)ROWS * CDIM;
  const size_t WSZ = (size_t)CDIM * CDIM;
  u16* ws0 = ws + 0 * PSZ;
  u16* ws1 = ws + 1 * PSZ;
  u16* ws2 = ws + 2 * PSZ;
  u16* Wb  = ws + 3 * PSZ;
  u16* Rhb = ws + 3 * PSZ + 4 * WSZ;
  u16* Rwb = Rhb + 64 * 64;
  u16* qbuf = (u16*)d_out;              // bf16 scratch inside f32 output buffer

  // 1) pool + layernorm (z=0: q; z=1: fused k+v)
  pool_ln_kernel<<<dim3(NOUT, 64, 2), 64, 0, stream>>>(
      x, xr, cwq, cwk, cwv, gq, lbq, gk, lbk, gv, lbv, ws0, ws1, ws2);

  // 2) weights + rel_pos -> bf16
  wcvt_kernel<<<(4 * CDIM * CDIM / 4 + 255) / 256, 256, 0, stream>>>(wq, wk, wv, wpj, Wb);
  rcvt_kernel<<<16, 256, 0, stream>>>(rph, rpw, Rhb, Rwb);

  // 3) q/k/v linear projections (MFMA) -> (b,h,n,d) bf16
  dim3 ggrid((ROWS + 127) / 128, CDIM / 128);
  mgemm_kernel<<<ggrid, 256, 0, stream>>>(ws0, Wb + 0 * WSZ, bq, qbuf, nullptr, ROWS, 1);
  mgemm_kernel<<<ggrid, 256, 0, stream>>>(ws1, Wb + 1 * WSZ, bk, ws0,  nullptr, ROWS, 1);
  mgemm_kernel<<<ggrid, 256, 0, stream>>>(ws2, Wb + 2 * WSZ, bv, ws1,  nullptr, ROWS, 1);

  // 4) attention (rel-pos fused) -> ws2
  fattn_kernel<<<dim3(NKT, 64), 256, 0, stream>>>(qbuf, ws0, ws1, Rhb, Rwb, ws2);

  // 5) output projection (MFMA) -> f32 d_out
  mgemm_kernel<<<ggrid, 256, 0, stream>>>(ws2, Wb + 3 * WSZ, bpj, nullptr, (float*)d_out, ROWS, 2);
}

// Round 10
// 249.040 us; speedup vs baseline: 12.9050x; 1.0673x over previous
//
#include <hip/hip_runtime.h>

// Problem constants (B=8, T=1, H=56, C=512, nh=8, d=64)
// Inputs: float32. Output: float32. ws intermediates: bf16.
#define NH    8
#define DH    64
#define NTOK  3137      // 56*56+1
#define NOUT  785       // 28*28+1
#define CDIM  512
#define ROWS  6280      // 8*785
#define HO    28
#define HIN   56
#define NKT   13        // ceil(785/64) key tiles
#define RELD  55        // 2*(56//2)-1

typedef unsigned short u16;
typedef __attribute__((ext_vector_type(8))) short bf16x8;   // 8 bf16 = 4 VGPRs
typedef __attribute__((ext_vector_type(4))) float f32x4;    // MFMA C/D

__device__ __forceinline__ float b2f(u16 u) { return __uint_as_float(((unsigned)u) << 16); }
__device__ __forceinline__ u16 f2b(float f) {
  unsigned u = __float_as_uint(f);
  return (u16)((u + 0x7FFFu + ((u >> 16) & 1u)) >> 16);
}

// ---------------------------------------------------------------------------
// Kernel 1: depthwise 3x3 stride-2 pool + LayerNorm(64).
// 4 waves/block, one token per wave. z=0: q from x. z=1: k AND v from x_ref.
// ---------------------------------------------------------------------------
__global__ __launch_bounds__(256) void pool_ln_kernel(
    const float* __restrict__ x, const float* __restrict__ xr,
    const float* __restrict__ cwq, const float* __restrict__ cwk, const float* __restrict__ cwv,
    const float* __restrict__ gq, const float* __restrict__ bq,
    const float* __restrict__ gk, const float* __restrict__ bk,
    const float* __restrict__ gv, const float* __restrict__ bv,
    u16* __restrict__ Pq, u16* __restrict__ Pk, u16* __restrict__ Pv)
{
  int n     = blockIdx.x * 4 + (threadIdx.x >> 6);   // token
  int bh    = blockIdx.y;
  int which = blockIdx.z;                            // 0=q(x), 1=k+v(x_ref)
  if (n >= NOUT) return;                             // wave-uniform
  int b = bh >> 3, h = bh & 7;
  int di = threadIdx.x & 63;

  const float* src = (which == 0) ? x : xr;
  size_t srcbase = (size_t)b * NTOK * CDIM + (size_t)h * DH + di;
  size_t obase = (size_t)(b * NOUT + n) * CDIM + h * DH + di;

  float vq = 0.f, vk = 0.f;
  const float* cw0 = (which == 0) ? cwq : cwk;

  if (n == 0) {
    float t = src[srcbase];
    vq = t; vk = t;
  } else {
    int oy = (n - 1) / HO, ox = (n - 1) % HO;
#pragma unroll
    for (int ky = 0; ky < 3; ++ky) {
      int iy = oy * 2 - 1 + ky;
      if (iy < 0 || iy >= HIN) continue;
#pragma unroll
      for (int kx = 0; kx < 3; ++kx) {
        int ix = ox * 2 - 1 + kx;
        if (ix < 0 || ix >= HIN) continue;
        int tok = 1 + iy * HIN + ix;
        float t = src[srcbase + (size_t)tok * CDIM];
        vq += t * cw0[(ky * 3 + kx) * DH + di];
        if (which == 1) vk += t * cwv[(ky * 3 + kx) * DH + di];
      }
    }
  }

  {
    float s = vq, sq = vq * vq;
#pragma unroll
    for (int off = 32; off > 0; off >>= 1) {
      s  += __shfl_xor(s, off, 64);
      sq += __shfl_xor(sq, off, 64);
    }
    float mu  = s * (1.f / 64.f);
    float var = sq * (1.f / 64.f) - mu * mu;
    const float* g  = (which == 0) ? gq : gk;
    const float* be = (which == 0) ? bq : bk;
    float o = (vq - mu) * rsqrtf(var + 1e-5f) * g[di] + be[di];
    ((which == 0) ? Pq : Pk)[obase] = f2b(o);
  }
  if (which == 1) {
    float s = vk, sq = vk * vk;
#pragma unroll
    for (int off = 32; off > 0; off >>= 1) {
      s  += __shfl_xor(s, off, 64);
      sq += __shfl_xor(sq, off, 64);
    }
    float mu  = s * (1.f / 64.f);
    float var = sq * (1.f / 64.f) - mu * mu;
    float o = (vk - mu) * rsqrtf(var + 1e-5f) * gv[di] + bv[di];
    Pv[obase] = f2b(o);
  }
}

// ---------------------------------------------------------------------------
// Kernel 2: convert the four 512x512 f32 weight matrices to bf16 (packed).
// ---------------------------------------------------------------------------
__global__ __launch_bounds__(256) void wcvt_kernel(
    const float* __restrict__ W0, const float* __restrict__ W1,
    const float* __restrict__ W2, const float* __restrict__ W3,
    u16* __restrict__ out)
{
  int idx = blockIdx.x * blockDim.x + threadIdx.x;
  const int per = CDIM * CDIM / 4;
  int mat = idx / per, off = (idx - mat * per) * 4;
  const float* src = (mat == 0) ? W0 : (mat == 1) ? W1 : (mat == 2) ? W2 : W3;
  float4 v = *(const float4*)(src + off);
  ushort4 o;
  o.x = f2b(v.x); o.y = f2b(v.y); o.z = f2b(v.z); o.w = f2b(v.w);
  *(ushort4*)(out + (size_t)mat * (CDIM * CDIM) + off) = o;
}

// ---------------------------------------------------------------------------
// Kernel 3: rel_pos f32 (55x64) -> bf16 padded [64][64] (rows >=55 zero).
// ---------------------------------------------------------------------------
__global__ __launch_bounds__(256) void rcvt_kernel(
    const float* __restrict__ rph, const float* __restrict__ rpw,
    u16* __restrict__ Rhb, u16* __restrict__ Rwb)
{
  int idx = blockIdx.x * blockDim.x + threadIdx.x;
  if (idx >= 64 * 64) return;
  int r = idx >> 6, d = idx & 63;
  Rhb[idx] = (r < RELD) ? f2b(rph[r * DH + d]) : 0;
  Rwb[idx] = (r < RELD) ? f2b(rpw[r * DH + d]) : 0;
}

// ---------------------------------------------------------------------------
// Kernel 4: MFMA GEMM (unchanged, verified round 8).
// ---------------------------------------------------------------------------
__global__ __launch_bounds__(256) void mgemm_kernel(
    const u16* __restrict__ X, const u16* __restrict__ Wb, const float* __restrict__ bias,
    u16* __restrict__ Yb16, float* __restrict__ Yf32, int R, int mode)
{
  int tid = threadIdx.x;
  int w = tid >> 6, lane = tid & 63, l15 = lane & 15, lg = lane >> 4;
  int m0 = blockIdx.x * 128 + (w >> 1) * 64;
  int n0 = blockIdx.y * 128 + (w & 1) * 64;

  f32x4 acc[4][4] = {};
  float bs[4];
#pragma unroll
  for (int nf = 0; nf < 4; ++nf) bs[nf] = bias[n0 + nf * 16 + l15];

  for (int k0 = 0; k0 < CDIM; k0 += 32) {
    bf16x8 a[4], b[4];
#pragma unroll
    for (int mf = 0; mf < 4; ++mf) {
      int r = m0 + mf * 16 + l15;
      if (r > R - 1) r = R - 1;
      a[mf] = *(const bf16x8*)(X + (size_t)r * CDIM + k0 + lg * 8);
    }
#pragma unroll
    for (int nf = 0; nf < 4; ++nf) {
      int co = n0 + nf * 16 + l15;
      b[nf] = *(const bf16x8*)(Wb + (size_t)co * CDIM + k0 + lg * 8);
    }
#pragma unroll
    for (int mf = 0; mf < 4; ++mf)
#pragma unroll
      for (int nf = 0; nf < 4; ++nf)
        acc[mf][nf] = __builtin_amdgcn_mfma_f32_16x16x32_bf16(a[mf], b[nf], acc[mf][nf], 0, 0, 0);
  }

#pragma unroll
  for (int mf = 0; mf < 4; ++mf) {
#pragma unroll
    for (int j = 0; j < 4; ++j) {
      int r = m0 + mf * 16 + lg * 4 + j;
      if (r >= R) continue;
      int bb = r / NOUT, n = r % NOUT;
#pragma unroll
      for (int nf = 0; nf < 4; ++nf) {
        int co = n0 + nf * 16 + l15;
        float v = acc[mf][nf][j] + bs[nf];
        if (mode == 1) {
          Yb16[(((size_t)bb * NH + (co >> 6)) * NOUT + n) * DH + (co & 63)] = f2b(v);
        } else {
          Yf32[(size_t)r * CDIM + co] = v;
        }
      }
    }
  }
}

// ---------------------------------------------------------------------------
// Kernel 5: flash-style MFMA attention, fused rel-pos, double-buffered V.
// One barrier per key tile; V(t+1) global loads issued before tile-t compute.
// Ps/rel tables are wave-private (no block barrier needed).
// ---------------------------------------------------------------------------
__global__ __launch_bounds__(256) void fattn_kernel(
    const u16* __restrict__ Q, const u16* __restrict__ K, const u16* __restrict__ V,
    const u16* __restrict__ Rhb, const u16* __restrict__ Rwb,
    u16* __restrict__ O)
{
  __shared__ u16 Qs[64][72];        // [q][d]
  __shared__ u16 Vs[2][64][64];     // [buf][d][k] XOR-swizzled
  __shared__ u16 Ps[4][16][72];     // per-wave P bounce
  __shared__ u16 relh[64][68];      // G_h[q][r]
  __shared__ u16 relw[64][68];      // G_w[q][r]

  int tid = threadIdx.x;
  int qt = blockIdx.x, bh = blockIdx.y;
  int w = tid >> 6, lane = tid & 63, l15 = lane & 15, lg = lane >> 4;
  size_t base = (size_t)bh * NOUT * DH;
  int q0 = qt * 64;

  // V-stage geometry (fixed per thread)
  int vkey_l = tid & 63;
  int vd0 = (tid >> 6) * 16;

  // ---- stage Q tile ----
  {
    int q = tid >> 2, d0 = (tid & 3) * 16;
    int qi = min(q0 + q, NOUT - 1);
    const u16* src = Q + base + (size_t)qi * DH + d0;
    bf16x8 a = *(const bf16x8*)(src);
    bf16x8 b = *(const bf16x8*)(src + 8);
    *(bf16x8*)&Qs[q][d0]     = a;
    *(bf16x8*)&Qs[q][d0 + 8] = b;
  }
  __syncthreads();

  // ---- Q A-fragments ----
  int qrow = w * 16 + l15;
  bf16x8 qa0 = *(const bf16x8*)&Qs[qrow][lg * 8];
  bf16x8 qa1 = *(const bf16x8*)&Qs[qrow][32 + lg * 8];

  // ---- prologue V stage: tile 0 -> Vs[0] ----
  {
    int key = min(vkey_l, NOUT - 1);
    const u16* vp = V + base + (size_t)key * DH + vd0;
    bf16x8 v0 = *(const bf16x8*)(vp);
    bf16x8 v1 = *(const bf16x8*)(vp + 8);
#pragma unroll
    for (int i = 0; i < 8; ++i) {
      int d = vd0 + i;
      Vs[0][d][((((vkey_l >> 3) ^ (d & 7)) << 3) | (vkey_l & 7))] = (u16)v0[i];
    }
#pragma unroll
    for (int i = 0; i < 8; ++i) {
      int d = vd0 + 8 + i;
      Vs[0][d][((((vkey_l >> 3) ^ (d & 7)) << 3) | (vkey_l & 7))] = (u16)v1[i];
    }
  }

  // ---- rel-pos tables via MFMA (wave-private rows) ----
#pragma unroll
  for (int nf = 0; nf < 4; ++nf) {
    int rr = nf * 16 + l15;
    const u16* hp = Rhb + rr * 64 + lg * 8;
    bf16x8 hb0 = *(const bf16x8*)(hp);
    bf16x8 hb1 = *(const bf16x8*)(hp + 32);
    f32x4 ah = {};
    ah = __builtin_amdgcn_mfma_f32_16x16x32_bf16(qa0, hb0, ah, 0, 0, 0);
    ah = __builtin_amdgcn_mfma_f32_16x16x32_bf16(qa1, hb1, ah, 0, 0, 0);
    const u16* wp = Rwb + rr * 64 + lg * 8;
    bf16x8 wb0 = *(const bf16x8*)(wp);
    bf16x8 wb1 = *(const bf16x8*)(wp + 32);
    f32x4 aw = {};
    aw = __builtin_amdgcn_mfma_f32_16x16x32_bf16(qa0, wb0, aw, 0, 0, 0);
    aw = __builtin_amdgcn_mfma_f32_16x16x32_bf16(qa1, wb1, aw, 0, 0, 0);
#pragma unroll
    for (int j = 0; j < 4; ++j) {
      relh[w * 16 + lg * 4 + j][rr] = f2b(ah[j]);
      relw[w * 16 + lg * 4 + j][rr] = f2b(aw[j]);
    }
  }

  // ---- per-j query row geometry ----
  int qy_j[4], qx_j[4];
  bool qv_j[4];
#pragma unroll
  for (int j = 0; j < 4; ++j) {
    int qi = q0 + w * 16 + lg * 4 + j;
    qv_j[j] = (qi >= 1);
    int qm1 = qi - 1;
    qy_j[j] = qm1 / HO;
    qx_j[j] = qm1 % HO;
  }

  f32x4 o0 = {}, o1 = {}, o2 = {}, o3 = {};
  float mrow[4], lrow[4];
#pragma unroll
  for (int j = 0; j < 4; ++j) { mrow[j] = -1e30f; lrow[j] = 0.f; }

  for (int t = 0; t < NKT; ++t) {
    int k0 = t * 64;
    int cur = t & 1;
    __syncthreads();   // Vs[cur] fully staged; prev tile's PV reads done

    // ---- issue next V tile's global loads FIRST (latency hides under compute)
    bf16x8 nv0, nv1;
    bool have_next = (t + 1 < NKT);
    if (have_next) {
      int key = min(k0 + 64 + vkey_l, NOUT - 1);
      const u16* vp = V + base + (size_t)key * DH + vd0;
      nv0 = *(const bf16x8*)(vp);
      nv1 = *(const bf16x8*)(vp + 8);
    }

    // ---- K fragment loads for this tile ----
    bf16x8 kb[4][2];
#pragma unroll
    for (int sub = 0; sub < 4; ++sub) {
      int key = k0 + sub * 16 + l15;
      int keff = min(key, NOUT - 1);
      const u16* kp = K + base + (size_t)keff * DH + lg * 8;
      kb[sub][0] = *(const bf16x8*)(kp);
      kb[sub][1] = *(const bf16x8*)(kp + 32);
    }

    // ---- S = scale*Q.K^T + bias ----
    f32x4 s[4];
#pragma unroll
    for (int sub = 0; sub < 4; ++sub) {
      int key = k0 + sub * 16 + l15;
      f32x4 acc = {};
      acc = __builtin_amdgcn_mfma_f32_16x16x32_bf16(qa0, kb[sub][0], acc, 0, 0, 0);
      acc = __builtin_amdgcn_mfma_f32_16x16x32_bf16(qa1, kb[sub][1], acc, 0, 0, 0);
      bool kv = key < NOUT;
      int km1 = key - 1;
      int ky = km1 / HO, kx = km1 % HO;
#pragma unroll
      for (int j = 0; j < 4; ++j) {
        float v = acc[j] * 0.125f;
        if (key >= 1 && kv && qv_j[j]) {
          int ql = w * 16 + lg * 4 + j;
          v += b2f(relh[ql][qy_j[j] - ky + 27]) + b2f(relw[ql][qx_j[j] - kx + 27]);
        }
        if (!kv) v = -1e30f;
        s[sub][j] = v;
      }
    }

    // ---- write next V tile into the idle buffer (no barrier needed) ----
    if (have_next) {
#pragma unroll
      for (int i = 0; i < 8; ++i) {
        int d = vd0 + i;
        Vs[cur ^ 1][d][((((vkey_l >> 3) ^ (d & 7)) << 3) | (vkey_l & 7))] = (u16)nv0[i];
      }
#pragma unroll
      for (int i = 0; i < 8; ++i) {
        int d = vd0 + 8 + i;
        Vs[cur ^ 1][d][((((vkey_l >> 3) ^ (d & 7)) << 3) | (vkey_l & 7))] = (u16)nv1[i];
      }
    }

    // ---- online softmax ----
    float alpha[4];
#pragma unroll
    for (int j = 0; j < 4; ++j) {
      float lm = fmaxf(fmaxf(s[0][j], s[1][j]), fmaxf(s[2][j], s[3][j]));
      lm = fmaxf(lm, __shfl_xor(lm, 1));
      lm = fmaxf(lm, __shfl_xor(lm, 2));
      lm = fmaxf(lm, __shfl_xor(lm, 4));
      lm = fmaxf(lm, __shfl_xor(lm, 8));
      float mnew = fmaxf(mrow[j], lm);
      alpha[j] = __expf(mrow[j] - mnew);
      mrow[j] = mnew;
      float ps = 0.f;
#pragma unroll
      for (int sub = 0; sub < 4; ++sub) {
        float pv = __expf(s[sub][j] - mnew);
        s[sub][j] = pv;
        ps += pv;
      }
      ps += __shfl_xor(ps, 1);
      ps += __shfl_xor(ps, 2);
      ps += __shfl_xor(ps, 4);
      ps += __shfl_xor(ps, 8);
      lrow[j] = lrow[j] * alpha[j] + ps;
    }

    // ---- rescale O, bounce P (wave-private) ----
#pragma unroll
    for (int j = 0; j < 4; ++j) {
      o0[j] *= alpha[j]; o1[j] *= alpha[j]; o2[j] *= alpha[j]; o3[j] *= alpha[j];
      Ps[w][lg * 4 + j][ 0 + l15] = f2b(s[0][j]);
      Ps[w][lg * 4 + j][16 + l15] = f2b(s[1][j]);
      Ps[w][lg * 4 + j][32 + l15] = f2b(s[2][j]);
      Ps[w][lg * 4 + j][48 + l15] = f2b(s[3][j]);
    }

    // ---- O += P.V from Vs[cur] ----
    bf16x8 pa0 = *(const bf16x8*)&Ps[w][l15][lg * 8];
    bf16x8 pa1 = *(const bf16x8*)&Ps[w][l15][32 + lg * 8];
    {
      int r = 0 + l15;
      bf16x8 vb0 = *(const bf16x8*)&Vs[cur][r][((lg ^ (r & 7)) << 3)];
      bf16x8 vb1 = *(const bf16x8*)&Vs[cur][r][(((4 + lg) ^ (r & 7)) << 3)];
      o0 = __builtin_amdgcn_mfma_f32_16x16x32_bf16(pa0, vb0, o0, 0, 0, 0);
      o0 = __builtin_amdgcn_mfma_f32_16x16x32_bf16(pa1, vb1, o0, 0, 0, 0);
    }
    {
      int r = 16 + l15;
      bf16x8 vb0 = *(const bf16x8*)&Vs[cur][r][((lg ^ (r & 7)) << 3)];
      bf16x8 vb1 = *(const bf16x8*)&Vs[cur][r][(((4 + lg) ^ (r & 7)) << 3)];
      o1 = __builtin_amdgcn_mfma_f32_16x16x32_bf16(pa0, vb0, o1, 0, 0, 0);
      o1 = __builtin_amdgcn_mfma_f32_16x16x32_bf16(pa1, vb1, o1, 0, 0, 0);
    }
    {
      int r = 32 + l15;
      bf16x8 vb0 = *(const bf16x8*)&Vs[cur][r][((lg ^ (r & 7)) << 3)];
      bf16x8 vb1 = *(const bf16x8*)&Vs[cur][r][(((4 + lg) ^ (r & 7)) << 3)];
      o2 = __builtin_amdgcn_mfma_f32_16x16x32_bf16(pa0, vb0, o2, 0, 0, 0);
      o2 = __builtin_amdgcn_mfma_f32_16x16x32_bf16(pa1, vb1, o2, 0, 0, 0);
    }
    {
      int r = 48 + l15;
      bf16x8 vb0 = *(const bf16x8*)&Vs[cur][r][((lg ^ (r & 7)) << 3)];
      bf16x8 vb1 = *(const bf16x8*)&Vs[cur][r][(((4 + lg) ^ (r & 7)) << 3)];
      o3 = __builtin_amdgcn_mfma_f32_16x16x32_bf16(pa0, vb0, o3, 0, 0, 0);
      o3 = __builtin_amdgcn_mfma_f32_16x16x32_bf16(pa1, vb1, o3, 0, 0, 0);
    }
  }

  // ---- epilogue ----
  int b = bh >> 3, h = bh & 7;
#pragma unroll
  for (int j = 0; j < 4; ++j) {
    int ql = w * 16 + lg * 4 + j;
    int qi = q0 + ql;
    if (qi >= NOUT) continue;
    float inv = 1.f / lrow[j];
    float v0 = o0[j] * inv, v1 = o1[j] * inv, v2 = o2[j] * inv, v3 = o3[j] * inv;
    if (qi > 0) {
      v0 += b2f(Qs[ql][ 0 + l15]);
      v1 += b2f(Qs[ql][16 + l15]);
      v2 += b2f(Qs[ql][32 + l15]);
      v3 += b2f(Qs[ql][48 + l15]);
    }
    size_t ob = ((size_t)b * NOUT + qi) * CDIM + h * DH;
    O[ob +  0 + l15] = f2b(v0);
    O[ob + 16 + l15] = f2b(v1);
    O[ob + 32 + l15] = f2b(v2);
    O[ob + 48 + l15] = f2b(v3);
  }
}

// ---------------------------------------------------------------------------
// ws layout (u16): ws0/ws1/ws2 (3 x PSZ), Wb (4 x 512*512), Rhb/Rwb (2 x 4096).
// Schedule: pool -> ws0,ws1,ws2 ; mgemm q->d_out(scratch) k->ws0 v->ws1 ;
//           fattn -> ws2 ; mgemm proj -> d_out (f32).
// ---------------------------------------------------------------------------
extern "C" void kernel_launch(void* const* d_in, const int* in_sizes, int n_in,
                              void* d_out, int out_size, void* d_ws, size_t ws_size,
                              hipStream_t stream) {
  const float* x     = (const float*)d_in[0];
  const float* xr    = (const float*)d_in[1];
  const float* wq    = (const float*)d_in[2];
  const float* bq    = (const float*)d_in[3];
  const float* wk    = (const float*)d_in[4];
  const float* bk    = (const float*)d_in[5];
  const float* wv    = (const float*)d_in[6];
  const float* bv    = (const float*)d_in[7];
  const float* wpj   = (const float*)d_in[8];
  const float* bpj   = (const float*)d_in[9];
  const float* cwq   = (const float*)d_in[10];
  const float* cwk   = (const float*)d_in[11];
  const float* cwv   = (const float*)d_in[12];
  const float* gq    = (const float*)d_in[13];
  const float* lbq   = (const float*)d_in[14];
  const float* gk    = (const float*)d_in[15];
  const float* lbk   = (const float*)d_in[16];
  const float* gv    = (const float*)d_in[17];
  const float* lbv   = (const float*)d_in[18];
  const float* rph   = (const float*)d_in[19];
  const float* rpw   = (const float*)d_in[20];
  (void)in_sizes; (void)n_in; (void)out_size; (void)ws_size;

  u16* ws = (u16*)d_ws;
  const size_t PSZ = (size_t)ROWS * CDIM;
  const size_t WSZ = (size_t)CDIM * CDIM;
  u16* ws0 = ws + 0 * PSZ;
  u16* ws1 = ws + 1 * PSZ;
  u16* ws2 = ws + 2 * PSZ;
  u16* Wb  = ws + 3 * PSZ;
  u16* Rhb = ws + 3 * PSZ + 4 * WSZ;
  u16* Rwb = Rhb + 64 * 64;
  u16* qbuf = (u16*)d_out;              // bf16 scratch inside f32 output buffer

  // 1) pool + layernorm (z=0: q; z=1: fused k+v)
  pool_ln_kernel<<<dim3((NOUT + 3) / 4, 64, 2), 256, 0, stream>>>(
      x, xr, cwq, cwk, cwv, gq, lbq, gk, lbk, gv, lbv, ws0, ws1, ws2);

  // 2) weights + rel_pos -> bf16
  wcvt_kernel<<<(4 * CDIM * CDIM / 4 + 255) / 256, 256, 0, stream>>>(wq, wk, wv, wpj, Wb);
  rcvt_kernel<<<16, 256, 0, stream>>>(rph, rpw, Rhb, Rwb);

  // 3) q/k/v linear projections (MFMA) -> (b,h,n,d) bf16
  dim3 ggrid((ROWS + 127) / 128, CDIM / 128);
  mgemm_kernel<<<ggrid, 256, 0, stream>>>(ws0, Wb + 0 * WSZ, bq, qbuf, nullptr, ROWS, 1);
  mgemm_kernel<<<ggrid, 256, 0, stream>>>(ws1, Wb + 1 * WSZ, bk, ws0,  nullptr, ROWS, 1);
  mgemm_kernel<<<ggrid, 256, 0, stream>>>(ws2, Wb + 2 * WSZ, bv, ws1,  nullptr, ROWS, 1);

  // 4) attention (rel-pos fused, V double-buffered) -> ws2
  fattn_kernel<<<dim3(NKT, 64), 256, 0, stream>>>(qbuf, ws0, ws1, Rhb, Rwb, ws2);

  // 5) output projection (MFMA) -> f32 d_out
  mgemm_kernel<<<ggrid, 256, 0, stream>>>(ws2, Wb + 3 * WSZ, bpj, nullptr, (float*)d_out, ROWS, 2);
}

// Round 11
// 243.399 us; speedup vs baseline: 13.2042x; 1.0232x over previous
//
#include <hip/hip_runtime.h>

// Problem constants (B=8, T=1, H=56, C=512, nh=8, d=64)
// Inputs: float32. Output: float32. ws intermediates: bf16.
#define NH    8
#define DH    64
#define NTOK  3137      // 56*56+1
#define NOUT  785       // 28*28+1
#define CDIM  512
#define ROWS  6280      // 8*785
#define HO    28
#define HIN   56
#define NKT   13        // ceil(785/64) key tiles
#define RELD  55        // 2*(56//2)-1

typedef unsigned short u16;
typedef __attribute__((ext_vector_type(8))) short bf16x8;   // 8 bf16 = 4 VGPRs
typedef __attribute__((ext_vector_type(4))) float f32x4;    // MFMA C/D

__device__ __forceinline__ float b2f(u16 u) { return __uint_as_float(((unsigned)u) << 16); }
__device__ __forceinline__ u16 f2b(float f) {
  unsigned u = __float_as_uint(f);
  return (u16)((u + 0x7FFFu + ((u >> 16) & 1u)) >> 16);
}

// ---------------------------------------------------------------------------
// Kernel 1: depthwise 3x3 stride-2 pool + LayerNorm(64).
// 4 waves/block, one token per wave. z=0: q from x. z=1: k AND v from x_ref.
// ---------------------------------------------------------------------------
__global__ __launch_bounds__(256) void pool_ln_kernel(
    const float* __restrict__ x, const float* __restrict__ xr,
    const float* __restrict__ cwq, const float* __restrict__ cwk, const float* __restrict__ cwv,
    const float* __restrict__ gq, const float* __restrict__ bq,
    const float* __restrict__ gk, const float* __restrict__ bk,
    const float* __restrict__ gv, const float* __restrict__ bv,
    u16* __restrict__ Pq, u16* __restrict__ Pk, u16* __restrict__ Pv)
{
  int n     = blockIdx.x * 4 + (threadIdx.x >> 6);   // token
  int bh    = blockIdx.y;
  int which = blockIdx.z;                            // 0=q(x), 1=k+v(x_ref)
  if (n >= NOUT) return;                             // wave-uniform
  int b = bh >> 3, h = bh & 7;
  int di = threadIdx.x & 63;

  const float* src = (which == 0) ? x : xr;
  size_t srcbase = (size_t)b * NTOK * CDIM + (size_t)h * DH + di;
  size_t obase = (size_t)(b * NOUT + n) * CDIM + h * DH + di;

  float vq = 0.f, vk = 0.f;
  const float* cw0 = (which == 0) ? cwq : cwk;

  if (n == 0) {
    float t = src[srcbase];
    vq = t; vk = t;
  } else {
    int oy = (n - 1) / HO, ox = (n - 1) % HO;
#pragma unroll
    for (int ky = 0; ky < 3; ++ky) {
      int iy = oy * 2 - 1 + ky;
      if (iy < 0 || iy >= HIN) continue;
#pragma unroll
      for (int kx = 0; kx < 3; ++kx) {
        int ix = ox * 2 - 1 + kx;
        if (ix < 0 || ix >= HIN) continue;
        int tok = 1 + iy * HIN + ix;
        float t = src[srcbase + (size_t)tok * CDIM];
        vq += t * cw0[(ky * 3 + kx) * DH + di];
        if (which == 1) vk += t * cwv[(ky * 3 + kx) * DH + di];
      }
    }
  }

  {
    float s = vq, sq = vq * vq;
#pragma unroll
    for (int off = 32; off > 0; off >>= 1) {
      s  += __shfl_xor(s, off, 64);
      sq += __shfl_xor(sq, off, 64);
    }
    float mu  = s * (1.f / 64.f);
    float var = sq * (1.f / 64.f) - mu * mu;
    const float* g  = (which == 0) ? gq : gk;
    const float* be = (which == 0) ? bq : bk;
    float o = (vq - mu) * rsqrtf(var + 1e-5f) * g[di] + be[di];
    ((which == 0) ? Pq : Pk)[obase] = f2b(o);
  }
  if (which == 1) {
    float s = vk, sq = vk * vk;
#pragma unroll
    for (int off = 32; off > 0; off >>= 1) {
      s  += __shfl_xor(s, off, 64);
      sq += __shfl_xor(sq, off, 64);
    }
    float mu  = s * (1.f / 64.f);
    float var = sq * (1.f / 64.f) - mu * mu;
    float o = (vk - mu) * rsqrtf(var + 1e-5f) * gv[di] + bv[di];
    Pv[obase] = f2b(o);
  }
}

// ---------------------------------------------------------------------------
// Kernel 2: convert the four 512x512 f32 weight matrices to bf16 (packed).
// ---------------------------------------------------------------------------
__global__ __launch_bounds__(256) void wcvt_kernel(
    const float* __restrict__ W0, const float* __restrict__ W1,
    const float* __restrict__ W2, const float* __restrict__ W3,
    u16* __restrict__ out)
{
  int idx = blockIdx.x * blockDim.x + threadIdx.x;
  const int per = CDIM * CDIM / 4;
  int mat = idx / per, off = (idx - mat * per) * 4;
  const float* src = (mat == 0) ? W0 : (mat == 1) ? W1 : (mat == 2) ? W2 : W3;
  float4 v = *(const float4*)(src + off);
  ushort4 o;
  o.x = f2b(v.x); o.y = f2b(v.y); o.z = f2b(v.z); o.w = f2b(v.w);
  *(ushort4*)(out + (size_t)mat * (CDIM * CDIM) + off) = o;
}

// ---------------------------------------------------------------------------
// Kernel 3: rel_pos f32 (55x64) -> bf16 padded [64][64] (rows >=55 zero).
// ---------------------------------------------------------------------------
__global__ __launch_bounds__(256) void rcvt_kernel(
    const float* __restrict__ rph, const float* __restrict__ rpw,
    u16* __restrict__ Rhb, u16* __restrict__ Rwb)
{
  int idx = blockIdx.x * blockDim.x + threadIdx.x;
  if (idx >= 64 * 64) return;
  int r = idx >> 6, d = idx & 63;
  Rhb[idx] = (r < RELD) ? f2b(rph[r * DH + d]) : 0;
  Rwb[idx] = (r < RELD) ? f2b(rpw[r * DH + d]) : 0;
}

// ---------------------------------------------------------------------------
// Kernel 4a: batched MFMA GEMM for q/k/v (z selects input/weight/bias/output).
// Tile 128x128, 4 waves, wave 64x64, K-chunk 32. Output bf16 (b,h,n,d).
// ---------------------------------------------------------------------------
__global__ __launch_bounds__(256) void mgemm3_kernel(
    const u16* __restrict__ Xq, const u16* __restrict__ Xk, const u16* __restrict__ Xv,
    const u16* __restrict__ Wb, const float* __restrict__ bq,
    const float* __restrict__ bk, const float* __restrict__ bv,
    u16* __restrict__ Yq, u16* __restrict__ Yk, u16* __restrict__ Yv)
{
  int z = blockIdx.z;
  const u16* X = (z == 0) ? Xq : (z == 1) ? Xk : Xv;
  const u16* W = Wb + (size_t)z * CDIM * CDIM;
  const float* bias = (z == 0) ? bq : (z == 1) ? bk : bv;
  u16* Y = (z == 0) ? Yq : (z == 1) ? Yk : Yv;

  int tid = threadIdx.x;
  int w = tid >> 6, lane = tid & 63, l15 = lane & 15, lg = lane >> 4;
  int m0 = blockIdx.x * 128 + (w >> 1) * 64;
  int n0 = blockIdx.y * 128 + (w & 1) * 64;

  f32x4 acc[4][4] = {};
  float bs[4];
#pragma unroll
  for (int nf = 0; nf < 4; ++nf) bs[nf] = bias[n0 + nf * 16 + l15];

  for (int k0 = 0; k0 < CDIM; k0 += 32) {
    bf16x8 a[4], b[4];
#pragma unroll
    for (int mf = 0; mf < 4; ++mf) {
      int r = m0 + mf * 16 + l15;
      if (r > ROWS - 1) r = ROWS - 1;
      a[mf] = *(const bf16x8*)(X + (size_t)r * CDIM + k0 + lg * 8);
    }
#pragma unroll
    for (int nf = 0; nf < 4; ++nf) {
      int co = n0 + nf * 16 + l15;
      b[nf] = *(const bf16x8*)(W + (size_t)co * CDIM + k0 + lg * 8);
    }
#pragma unroll
    for (int mf = 0; mf < 4; ++mf)
#pragma unroll
      for (int nf = 0; nf < 4; ++nf)
        acc[mf][nf] = __builtin_amdgcn_mfma_f32_16x16x32_bf16(a[mf], b[nf], acc[mf][nf], 0, 0, 0);
  }

#pragma unroll
  for (int mf = 0; mf < 4; ++mf) {
#pragma unroll
    for (int j = 0; j < 4; ++j) {
      int r = m0 + mf * 16 + lg * 4 + j;
      if (r >= ROWS) continue;
      int bb = r / NOUT, n = r % NOUT;
#pragma unroll
      for (int nf = 0; nf < 4; ++nf) {
        int co = n0 + nf * 16 + l15;
        float v = acc[mf][nf][j] + bs[nf];
        Y[(((size_t)bb * NH + (co >> 6)) * NOUT + n) * DH + (co & 63)] = f2b(v);
      }
    }
  }
}

// ---------------------------------------------------------------------------
// Kernel 4b: proj MFMA GEMM -> f32 row-major d_out. (single matrix)
// ---------------------------------------------------------------------------
__global__ __launch_bounds__(256) void mgemm_proj_kernel(
    const u16* __restrict__ X, const u16* __restrict__ Wb, const float* __restrict__ bias,
    float* __restrict__ Y)
{
  int tid = threadIdx.x;
  int w = tid >> 6, lane = tid & 63, l15 = lane & 15, lg = lane >> 4;
  int m0 = blockIdx.x * 128 + (w >> 1) * 64;
  int n0 = blockIdx.y * 128 + (w & 1) * 64;

  f32x4 acc[4][4] = {};
  float bs[4];
#pragma unroll
  for (int nf = 0; nf < 4; ++nf) bs[nf] = bias[n0 + nf * 16 + l15];

  for (int k0 = 0; k0 < CDIM; k0 += 32) {
    bf16x8 a[4], b[4];
#pragma unroll
    for (int mf = 0; mf < 4; ++mf) {
      int r = m0 + mf * 16 + l15;
      if (r > ROWS - 1) r = ROWS - 1;
      a[mf] = *(const bf16x8*)(X + (size_t)r * CDIM + k0 + lg * 8);
    }
#pragma unroll
    for (int nf = 0; nf < 4; ++nf) {
      int co = n0 + nf * 16 + l15;
      b[nf] = *(const bf16x8*)(Wb + (size_t)co * CDIM + k0 + lg * 8);
    }
#pragma unroll
    for (int mf = 0; mf < 4; ++mf)
#pragma unroll
      for (int nf = 0; nf < 4; ++nf)
        acc[mf][nf] = __builtin_amdgcn_mfma_f32_16x16x32_bf16(a[mf], b[nf], acc[mf][nf], 0, 0, 0);
  }

#pragma unroll
  for (int mf = 0; mf < 4; ++mf) {
#pragma unroll
    for (int j = 0; j < 4; ++j) {
      int r = m0 + mf * 16 + lg * 4 + j;
      if (r >= ROWS) continue;
#pragma unroll
      for (int nf = 0; nf < 4; ++nf) {
        int co = n0 + nf * 16 + l15;
        Y[(size_t)r * CDIM + co] = acc[mf][nf][j] + bs[nf];
      }
    }
  }
}

// ---------------------------------------------------------------------------
// Kernel 5: flash-style MFMA attention. LDS ~40 KB (4 blocks/CU):
// no Qs (Q read direct from global, L2-hot), rel tables [64][57],
// double-buffered swizzled Vs, XCD-aware 1D grid (832 = 13*64 blocks).
// ---------------------------------------------------------------------------
__global__ __launch_bounds__(256, 4) void fattn_kernel(
    const u16* __restrict__ Q, const u16* __restrict__ K, const u16* __restrict__ V,
    const u16* __restrict__ Rhb, const u16* __restrict__ Rwb,
    u16* __restrict__ O)
{
  __shared__ u16 Vs[2][64][64];     // [buf][d][k] XOR-swizzled      16384 B
  __shared__ u16 Ps[4][16][72];     // per-wave P bounce              9216 B
  __shared__ u16 relh[64][57];      // G_h[q][r]                      7296 B
  __shared__ u16 relw[64][57];      //                                7296 B

  // XCD-aware block swizzle: 832 blocks, 8 XCDs, 104 blocks/XCD.
  // All 13 q-tiles of a bh land on the same XCD -> K/V L2 reuse.
  int bid = blockIdx.x;
  int nbid = (bid & 7) * 104 + (bid >> 3);
  int bh = nbid / NKT, qt = nbid % NKT;

  int tid = threadIdx.x;
  int w = tid >> 6, lane = tid & 63, l15 = lane & 15, lg = lane >> 4;
  size_t base = (size_t)bh * NOUT * DH;
  int q0 = qt * 64;

  // V-stage geometry (fixed per thread)
  int vkey_l = tid & 63;
  int vd0 = (tid >> 6) * 16;

  // ---- Q A-fragments direct from global ----
  int qrow_qi = min(q0 + w * 16 + l15, NOUT - 1);
  const u16* qp = Q + base + (size_t)qrow_qi * DH + lg * 8;
  bf16x8 qa0 = *(const bf16x8*)(qp);
  bf16x8 qa1 = *(const bf16x8*)(qp + 32);

  // ---- prologue V stage: tile 0 -> Vs[0] ----
  {
    int key = min(vkey_l, NOUT - 1);
    const u16* vp = V + base + (size_t)key * DH + vd0;
    bf16x8 v0 = *(const bf16x8*)(vp);
    bf16x8 v1 = *(const bf16x8*)(vp + 8);
#pragma unroll
    for (int i = 0; i < 8; ++i) {
      int d = vd0 + i;
      Vs[0][d][((((vkey_l >> 3) ^ (d & 7)) << 3) | (vkey_l & 7))] = (u16)v0[i];
    }
#pragma unroll
    for (int i = 0; i < 8; ++i) {
      int d = vd0 + 8 + i;
      Vs[0][d][((((vkey_l >> 3) ^ (d & 7)) << 3) | (vkey_l & 7))] = (u16)v1[i];
    }
  }

  // ---- rel-pos tables via MFMA (wave-private rows) ----
#pragma unroll
  for (int nf = 0; nf < 4; ++nf) {
    int rr = nf * 16 + l15;
    const u16* hp = Rhb + rr * 64 + lg * 8;
    bf16x8 hb0 = *(const bf16x8*)(hp);
    bf16x8 hb1 = *(const bf16x8*)(hp + 32);
    f32x4 ah = {};
    ah = __builtin_amdgcn_mfma_f32_16x16x32_bf16(qa0, hb0, ah, 0, 0, 0);
    ah = __builtin_amdgcn_mfma_f32_16x16x32_bf16(qa1, hb1, ah, 0, 0, 0);
    const u16* wp = Rwb + rr * 64 + lg * 8;
    bf16x8 wb0 = *(const bf16x8*)(wp);
    bf16x8 wb1 = *(const bf16x8*)(wp + 32);
    f32x4 aw = {};
    aw = __builtin_amdgcn_mfma_f32_16x16x32_bf16(qa0, wb0, aw, 0, 0, 0);
    aw = __builtin_amdgcn_mfma_f32_16x16x32_bf16(qa1, wb1, aw, 0, 0, 0);
    if (rr < 57) {
#pragma unroll
      for (int j = 0; j < 4; ++j) {
        relh[w * 16 + lg * 4 + j][rr] = f2b(ah[j]);
        relw[w * 16 + lg * 4 + j][rr] = f2b(aw[j]);
      }
    }
  }

  // ---- per-j query row geometry ----
  int qy_j[4], qx_j[4];
  bool qv_j[4];
#pragma unroll
  for (int j = 0; j < 4; ++j) {
    int qi = q0 + w * 16 + lg * 4 + j;
    qv_j[j] = (qi >= 1);
    int qm1 = qi - 1;
    qy_j[j] = qm1 / HO;
    qx_j[j] = qm1 % HO;
  }

  f32x4 o0 = {}, o1 = {}, o2 = {}, o3 = {};
  float mrow[4], lrow[4];
#pragma unroll
  for (int j = 0; j < 4; ++j) { mrow[j] = -1e30f; lrow[j] = 0.f; }

  for (int t = 0; t < NKT; ++t) {
    int k0 = t * 64;
    int cur = t & 1;
    __syncthreads();   // Vs[cur] fully staged; prev tile's PV reads done

    // ---- issue next V tile's global loads FIRST ----
    bf16x8 nv0, nv1;
    bool have_next = (t + 1 < NKT);
    if (have_next) {
      int key = min(k0 + 64 + vkey_l, NOUT - 1);
      const u16* vp = V + base + (size_t)key * DH + vd0;
      nv0 = *(const bf16x8*)(vp);
      nv1 = *(const bf16x8*)(vp + 8);
    }

    // ---- K fragment loads for this tile ----
    bf16x8 kb[4][2];
#pragma unroll
    for (int sub = 0; sub < 4; ++sub) {
      int key = k0 + sub * 16 + l15;
      int keff = min(key, NOUT - 1);
      const u16* kp = K + base + (size_t)keff * DH + lg * 8;
      kb[sub][0] = *(const bf16x8*)(kp);
      kb[sub][1] = *(const bf16x8*)(kp + 32);
    }

    // ---- S = scale*Q.K^T + bias ----
    f32x4 s[4];
#pragma unroll
    for (int sub = 0; sub < 4; ++sub) {
      int key = k0 + sub * 16 + l15;
      f32x4 acc = {};
      acc = __builtin_amdgcn_mfma_f32_16x16x32_bf16(qa0, kb[sub][0], acc, 0, 0, 0);
      acc = __builtin_amdgcn_mfma_f32_16x16x32_bf16(qa1, kb[sub][1], acc, 0, 0, 0);
      bool kv = key < NOUT;
      int km1 = key - 1;
      int ky = km1 / HO, kx = km1 % HO;
#pragma unroll
      for (int j = 0; j < 4; ++j) {
        float v = acc[j] * 0.125f;
        if (key >= 1 && kv && qv_j[j]) {
          int ql = w * 16 + lg * 4 + j;
          v += b2f(relh[ql][qy_j[j] - ky + 27]) + b2f(relw[ql][qx_j[j] - kx + 27]);
        }
        if (!kv) v = -1e30f;
        s[sub][j] = v;
      }
    }

    // ---- write next V tile into idle buffer (no barrier needed) ----
    if (have_next) {
#pragma unroll
      for (int i = 0; i < 8; ++i) {
        int d = vd0 + i;
        Vs[cur ^ 1][d][((((vkey_l >> 3) ^ (d & 7)) << 3) | (vkey_l & 7))] = (u16)nv0[i];
      }
#pragma unroll
      for (int i = 0; i < 8; ++i) {
        int d = vd0 + 8 + i;
        Vs[cur ^ 1][d][((((vkey_l >> 3) ^ (d & 7)) << 3) | (vkey_l & 7))] = (u16)nv1[i];
      }
    }

    // ---- online softmax ----
    float alpha[4];
#pragma unroll
    for (int j = 0; j < 4; ++j) {
      float lm = fmaxf(fmaxf(s[0][j], s[1][j]), fmaxf(s[2][j], s[3][j]));
      lm = fmaxf(lm, __shfl_xor(lm, 1));
      lm = fmaxf(lm, __shfl_xor(lm, 2));
      lm = fmaxf(lm, __shfl_xor(lm, 4));
      lm = fmaxf(lm, __shfl_xor(lm, 8));
      float mnew = fmaxf(mrow[j], lm);
      alpha[j] = __expf(mrow[j] - mnew);
      mrow[j] = mnew;
      float ps = 0.f;
#pragma unroll
      for (int sub = 0; sub < 4; ++sub) {
        float pv = __expf(s[sub][j] - mnew);
        s[sub][j] = pv;
        ps += pv;
      }
      ps += __shfl_xor(ps, 1);
      ps += __shfl_xor(ps, 2);
      ps += __shfl_xor(ps, 4);
      ps += __shfl_xor(ps, 8);
      lrow[j] = lrow[j] * alpha[j] + ps;
    }

    // ---- rescale O, bounce P (wave-private) ----
#pragma unroll
    for (int j = 0; j < 4; ++j) {
      o0[j] *= alpha[j]; o1[j] *= alpha[j]; o2[j] *= alpha[j]; o3[j] *= alpha[j];
      Ps[w][lg * 4 + j][ 0 + l15] = f2b(s[0][j]);
      Ps[w][lg * 4 + j][16 + l15] = f2b(s[1][j]);
      Ps[w][lg * 4 + j][32 + l15] = f2b(s[2][j]);
      Ps[w][lg * 4 + j][48 + l15] = f2b(s[3][j]);
    }

    // ---- O += P.V from Vs[cur] ----
    bf16x8 pa0 = *(const bf16x8*)&Ps[w][l15][lg * 8];
    bf16x8 pa1 = *(const bf16x8*)&Ps[w][l15][32 + lg * 8];
    {
      int r = 0 + l15;
      bf16x8 vb0 = *(const bf16x8*)&Vs[cur][r][((lg ^ (r & 7)) << 3)];
      bf16x8 vb1 = *(const bf16x8*)&Vs[cur][r][(((4 + lg) ^ (r & 7)) << 3)];
      o0 = __builtin_amdgcn_mfma_f32_16x16x32_bf16(pa0, vb0, o0, 0, 0, 0);
      o0 = __builtin_amdgcn_mfma_f32_16x16x32_bf16(pa1, vb1, o0, 0, 0, 0);
    }
    {
      int r = 16 + l15;
      bf16x8 vb0 = *(const bf16x8*)&Vs[cur][r][((lg ^ (r & 7)) << 3)];
      bf16x8 vb1 = *(const bf16x8*)&Vs[cur][r][(((4 + lg) ^ (r & 7)) << 3)];
      o1 = __builtin_amdgcn_mfma_f32_16x16x32_bf16(pa0, vb0, o1, 0, 0, 0);
      o1 = __builtin_amdgcn_mfma_f32_16x16x32_bf16(pa1, vb1, o1, 0, 0, 0);
    }
    {
      int r = 32 + l15;
      bf16x8 vb0 = *(const bf16x8*)&Vs[cur][r][((lg ^ (r & 7)) << 3)];
      bf16x8 vb1 = *(const bf16x8*)&Vs[cur][r][(((4 + lg) ^ (r & 7)) << 3)];
      o2 = __builtin_amdgcn_mfma_f32_16x16x32_bf16(pa0, vb0, o2, 0, 0, 0);
      o2 = __builtin_amdgcn_mfma_f32_16x16x32_bf16(pa1, vb1, o2, 0, 0, 0);
    }
    {
      int r = 48 + l15;
      bf16x8 vb0 = *(const bf16x8*)&Vs[cur][r][((lg ^ (r & 7)) << 3)];
      bf16x8 vb1 = *(const bf16x8*)&Vs[cur][r][(((4 + lg) ^ (r & 7)) << 3)];
      o3 = __builtin_amdgcn_mfma_f32_16x16x32_bf16(pa0, vb0, o3, 0, 0, 0);
      o3 = __builtin_amdgcn_mfma_f32_16x16x32_bf16(pa1, vb1, o3, 0, 0, 0);
    }
  }

  // ---- epilogue: normalize, residual (Q re-read from global), store ----
  int b = bh >> 3, h = bh & 7;
#pragma unroll
  for (int j = 0; j < 4; ++j) {
    int ql = w * 16 + lg * 4 + j;
    int qi = q0 + ql;
    if (qi >= NOUT) continue;
    float inv = 1.f / lrow[j];
    float v0 = o0[j] * inv, v1 = o1[j] * inv, v2 = o2[j] * inv, v3 = o3[j] * inv;
    if (qi > 0) {
      const u16* qp2 = Q + base + (size_t)qi * DH;
      v0 += b2f(qp2[ 0 + l15]);
      v1 += b2f(qp2[16 + l15]);
      v2 += b2f(qp2[32 + l15]);
      v3 += b2f(qp2[48 + l15]);
    }
    size_t ob = ((size_t)b * NOUT + qi) * CDIM + h * DH;
    O[ob +  0 + l15] = f2b(v0);
    O[ob + 16 + l15] = f2b(v1);
    O[ob + 32 + l15] = f2b(v2);
    O[ob + 48 + l15] = f2b(v3);
  }
}

// ---------------------------------------------------------------------------
// ws layout (u16): ws0/ws1/ws2 (3 x PSZ), Wb (4 x 512*512), Rhb/Rwb (2 x 4096).
// Schedule: pool -> ws0,ws1,ws2 ; mgemm3 q->d_out(scratch) k->ws0 v->ws1
//   (reads ws0/ws1/ws2 before overwrite: q writes d_out, k writes... note
//    k output ws0 is also k's input? No: inputs Pq=ws0,Pk=ws1,Pv=ws2; outputs
//    q->qbuf, k->ws0, v->ws1 -- k reads ws1 writes ws0 (ws0's Pq consumed by
//    z=0 concurrently). All three z-slices read all inputs before any is
//    overwritten? z=0 reads ws0, z=1 writes ws0. RACE across z-slices!
//    Fix: v->ws2 is also input of z=2. Use disjoint outputs: q->qbuf,
//    k->Wb+..? Instead outputs go to fresh regions: k->ws3, v->ws4 where
//    ws3/ws4 are extra PSZ buffers (ws usage 5*PSZ+Wb+tables = 34.5 MB < 45).
// fattn -> ws2 is dead after v gemm... fattn reads qbuf,ws3,ws4 -> writes ws0.
// proj reads ws0 -> d_out.
// ---------------------------------------------------------------------------
extern "C" void kernel_launch(void* const* d_in, const int* in_sizes, int n_in,
                              void* d_out, int out_size, void* d_ws, size_t ws_size,
                              hipStream_t stream) {
  const float* x     = (const float*)d_in[0];
  const float* xr    = (const float*)d_in[1];
  const float* wq    = (const float*)d_in[2];
  const float* bq    = (const float*)d_in[3];
  const float* wk    = (const float*)d_in[4];
  const float* bk    = (const float*)d_in[5];
  const float* wv    = (const float*)d_in[6];
  const float* bv    = (const float*)d_in[7];
  const float* wpj   = (const float*)d_in[8];
  const float* bpj   = (const float*)d_in[9];
  const float* cwq   = (const float*)d_in[10];
  const float* cwk   = (const float*)d_in[11];
  const float* cwv   = (const float*)d_in[12];
  const float* gq    = (const float*)d_in[13];
  const float* lbq   = (const float*)d_in[14];
  const float* gk    = (const float*)d_in[15];
  const float* lbk   = (const float*)d_in[16];
  const float* gv    = (const float*)d_in[17];
  const float* lbv   = (const float*)d_in[18];
  const float* rph   = (const float*)d_in[19];
  const float* rpw   = (const float*)d_in[20];
  (void)in_sizes; (void)n_in; (void)out_size; (void)ws_size;

  u16* ws = (u16*)d_ws;
  const size_t PSZ = (size_t)ROWS * CDIM;
  const size_t WSZ = (size_t)CDIM * CDIM;
  u16* ws0 = ws + 0 * PSZ;
  u16* ws1 = ws + 1 * PSZ;
  u16* ws2 = ws + 2 * PSZ;
  u16* ws3 = ws + 3 * PSZ;
  u16* ws4 = ws + 4 * PSZ;
  u16* Wb  = ws + 5 * PSZ;
  u16* Rhb = ws + 5 * PSZ + 4 * WSZ;
  u16* Rwb = Rhb + 64 * 64;
  u16* qbuf = (u16*)d_out;              // bf16 scratch inside f32 output buffer

  // 1) pool + layernorm (z=0: q; z=1: fused k+v) -> Pq=ws0, Pk=ws1, Pv=ws2
  pool_ln_kernel<<<dim3((NOUT + 3) / 4, 64, 2), 256, 0, stream>>>(
      x, xr, cwq, cwk, cwv, gq, lbq, gk, lbk, gv, lbv, ws0, ws1, ws2);

  // 2) weights + rel_pos -> bf16
  wcvt_kernel<<<(4 * CDIM * CDIM / 4 + 255) / 256, 256, 0, stream>>>(wq, wk, wv, wpj, Wb);
  rcvt_kernel<<<16, 256, 0, stream>>>(rph, rpw, Rhb, Rwb);

  // 3) q/k/v linear projections, one batched launch (disjoint in/out)
  //    q: ws0 -> qbuf ; k: ws1 -> ws3 ; v: ws2 -> ws4
  dim3 g3((ROWS + 127) / 128, CDIM / 128, 3);
  mgemm3_kernel<<<g3, 256, 0, stream>>>(ws0, ws1, ws2, Wb, bq, bk, bv, qbuf, ws3, ws4);

  // 4) attention (rel-pos fused, V dbuf, XCD swizzle) -> ws0
  fattn_kernel<<<NKT * 64, 256, 0, stream>>>(qbuf, ws3, ws4, Rhb, Rwb, ws0);

  // 5) output projection (MFMA) -> f32 d_out
  dim3 ggrid((ROWS + 127) / 128, CDIM / 128);
  mgemm_proj_kernel<<<ggrid, 256, 0, stream>>>(ws0, Wb + 3 * WSZ, bpj, (float*)d_out);
}